// Round 1
// baseline (770.911 us; speedup 1.0000x reference)
//
#include <hip/hip_runtime.h>
#include <math.h>

// GAT 2-layer, N=100000, E=1600000, F_IN=128, HID=128 (H=4,C=32), OUT=64 (H=1,C=64)
// Strategy: build dst-CSR once (hist + scan + scatter), then per layer:
//   f32 tiled GEMM -> per-node alpha_s/alpha_d -> wave-per-node softmax-aggregate
// No float atomics anywhere; softmax max-subtraction skipped (values ~N(0,0.25),
// mathematically identical ratio, exp can't overflow).

// ---------------- CSR build ----------------

__global__ void zero_kernel(int* p, int n) {
    int i = blockIdx.x * blockDim.x + threadIdx.x;
    if (i < n) p[i] = 0;
}

__global__ void hist_kernel(const int* __restrict__ ei, int E, int N, int* __restrict__ deg) {
    int k = blockIdx.x * blockDim.x + threadIdx.x;
    int Etot = E + N;
    if (k >= Etot) return;
    int d = (k < E) ? ei[E + k] : (k - E);
    atomicAdd(&deg[d], 1);
}

__global__ void scan_bsum(const int* __restrict__ deg, int* __restrict__ bsum, int N) {
    __shared__ int sdata[256];
    int b = blockIdx.x, t = threadIdx.x;
    int base = b * 1024 + t * 4;
    int s = 0;
#pragma unroll
    for (int i = 0; i < 4; ++i) {
        int idx = base + i;
        if (idx < N) s += deg[idx];
    }
    sdata[t] = s;
    __syncthreads();
    for (int o = 128; o > 0; o >>= 1) {
        if (t < o) sdata[t] += sdata[t + o];
        __syncthreads();
    }
    if (t == 0) bsum[b] = sdata[0];
}

__global__ void scan_serial(int* bsum, int nb) {
    if (blockIdx.x == 0 && threadIdx.x == 0) {
        int run = 0;
        for (int i = 0; i < nb; ++i) { int t = bsum[i]; bsum[i] = run; run += t; }
    }
}

__global__ void scan_final(const int* __restrict__ deg, const int* __restrict__ bsum,
                           int* __restrict__ offs, int* __restrict__ cursor, int N, int Etot) {
    __shared__ int sdata[256];
    int b = blockIdx.x, t = threadIdx.x;
    int base = b * 1024 + t * 4;
    int v[4];
    int sum = 0;
#pragma unroll
    for (int i = 0; i < 4; ++i) {
        int idx = base + i;
        v[i] = (idx < N) ? deg[idx] : 0;
        sum += v[i];
    }
    sdata[t] = sum;
    __syncthreads();
    // inclusive Hillis-Steele over 256 thread sums
    for (int o = 1; o < 256; o <<= 1) {
        int add = (t >= o) ? sdata[t - o] : 0;
        __syncthreads();
        sdata[t] += add;
        __syncthreads();
    }
    int excl = sdata[t] - sum;
    int run = bsum[b] + excl;
#pragma unroll
    for (int i = 0; i < 4; ++i) {
        int idx = base + i;
        if (idx < N) { offs[idx] = run; cursor[idx] = run; }
        run += v[i];
    }
    if (b == 0 && t == 0) offs[N] = Etot;
}

__global__ void scatter_kernel(const int* __restrict__ ei, int E, int N,
                               int* __restrict__ cursor, int* __restrict__ srcs) {
    int k = blockIdx.x * blockDim.x + threadIdx.x;
    int Etot = E + N;
    if (k >= Etot) return;
    int s, d;
    if (k < E) { s = ei[k]; d = ei[E + k]; } else { s = d = k - E; }
    int pos = atomicAdd(&cursor[d], 1);
    srcs[pos] = s;
}

// ---------------- GEMM: C[M,NC] = A[M,128] * B[128,NC] ----------------

template <int NC>
__global__ __launch_bounds__(256) void gemm_k128(const float* __restrict__ A,
                                                 const float* __restrict__ B,
                                                 float* __restrict__ C, int M) {
    constexpr int BM = 64, BK = 32, K = 128;
    constexpr int TPR = NC / 4;    // threads covering NC cols via float4
    constexpr int R = BM / (256 / TPR);  // rows per thread (8 or 4)
    __shared__ float AsT[BK][BM];
    __shared__ float Bs[BK][NC];
    int tid = threadIdx.x;
    int tx = tid % TPR, ty = tid / TPR;
    int rowBase = blockIdx.x * BM;
    float acc[R][4] = {};
    for (int k0 = 0; k0 < K; k0 += BK) {
        // load A tile (64x32) transposed, as float2
#pragma unroll
        for (int i = 0; i < 4; ++i) {
            int lin = tid + i * 256;     // 0..1023 float2 slots
            int row = lin >> 4;          // 16 float2 per row
            int kp = lin & 15;
            int grow = rowBase + row;
            if (grow >= M) grow = M - 1;
            float2 v = *reinterpret_cast<const float2*>(A + (size_t)grow * K + k0 + kp * 2);
            AsT[kp * 2][row] = v.x;
            AsT[kp * 2 + 1][row] = v.y;
        }
        // load B tile (32xNC)
#pragma unroll
        for (int i = 0; i < (BK * NC) / 1024; ++i) {
            int lin = tid + i * 256;     // float4 index
            int row = lin / (NC / 4);
            int col4 = lin % (NC / 4);
            float4 v = *reinterpret_cast<const float4*>(B + (size_t)(k0 + row) * NC + col4 * 4);
            *reinterpret_cast<float4*>(&Bs[row][col4 * 4]) = v;
        }
        __syncthreads();
#pragma unroll
        for (int kk = 0; kk < BK; ++kk) {
            float4 bv = *reinterpret_cast<const float4*>(&Bs[kk][tx * 4]);
            float a[R];
#pragma unroll
            for (int r4 = 0; r4 < R; r4 += 4) {
                float4 av = *reinterpret_cast<const float4*>(&AsT[kk][ty * R + r4]);
                a[r4] = av.x; a[r4 + 1] = av.y; a[r4 + 2] = av.z; a[r4 + 3] = av.w;
            }
#pragma unroll
            for (int r = 0; r < R; ++r) {
                acc[r][0] = fmaf(a[r], bv.x, acc[r][0]);
                acc[r][1] = fmaf(a[r], bv.y, acc[r][1]);
                acc[r][2] = fmaf(a[r], bv.z, acc[r][2]);
                acc[r][3] = fmaf(a[r], bv.w, acc[r][3]);
            }
        }
        __syncthreads();
    }
#pragma unroll
    for (int r = 0; r < R; ++r) {
        int grow = rowBase + ty * R + r;
        if (grow < M) {
            float4 v = make_float4(acc[r][0], acc[r][1], acc[r][2], acc[r][3]);
            *reinterpret_cast<float4*>(C + (size_t)grow * NC + tx * 4) = v;
        }
    }
}

// ---------------- alpha_s / alpha_d: per-node head dot products ----------------

template <int H, int C>
__global__ __launch_bounds__(256) void alphas_kernel(const float* __restrict__ h,
                                                     const float* __restrict__ a_src,
                                                     const float* __restrict__ a_dst,
                                                     float* __restrict__ as,
                                                     float* __restrict__ ad, int N) {
    constexpr int F = H * C;
    constexpr int PER = F / 64;   // elements per lane (2 or 1)
    int wid = (blockIdx.x * blockDim.x + threadIdx.x) >> 6;
    int lane = threadIdx.x & 63;
    if (wid >= N) return;
    float s = 0.f, d = 0.f;
#pragma unroll
    for (int p = 0; p < PER; ++p) {
        int f = lane * PER + p;
        float hv = h[(size_t)wid * F + f];
        s += hv * a_src[f];
        d += hv * a_dst[f];
    }
    constexpr int G = C / PER;    // lanes per head group (16 or 64)
#pragma unroll
    for (int o = 1; o < G; o <<= 1) {
        s += __shfl_xor(s, o, 64);
        d += __shfl_xor(d, o, 64);
    }
    if ((lane & (G - 1)) == 0) {
        int head = (lane * PER) / C;
        as[(size_t)wid * H + head] = s;
        ad[(size_t)wid * H + head] = d;
    }
}

// ---------------- aggregation (wave per dst node) ----------------

// Layer 1: F=128, H=4, C=32; fused bias + ELU epilogue.
__global__ __launch_bounds__(256) void aggregate1(const float* __restrict__ h,
                                                  const float* __restrict__ as,
                                                  const float* __restrict__ ad,
                                                  const int* __restrict__ offs,
                                                  const int* __restrict__ srcs,
                                                  const float* __restrict__ bias,
                                                  float* __restrict__ out, int N) {
    int wid = (blockIdx.x * blockDim.x + threadIdx.x) >> 6;
    int lane = threadIdx.x & 63;
    if (wid >= N) return;
    int head = lane >> 4;                 // c = 2*lane, 2*lane+1 -> head = lane/16
    float adv = ad[(size_t)wid * 4 + head];
    int e0 = offs[wid], e1 = offs[wid + 1];
    float acc0 = 0.f, acc1 = 0.f, den = 0.f;
    for (int e = e0; e < e1; ++e) {
        int j = srcs[e];
        float t = as[(size_t)j * 4 + head] + adv;
        t = (t > 0.f) ? t : 0.2f * t;     // leaky_relu
        float ex = expf(t);
        float2 hv = *reinterpret_cast<const float2*>(h + (size_t)j * 128 + 2 * lane);
        acc0 = fmaf(ex, hv.x, acc0);
        acc1 = fmaf(ex, hv.y, acc1);
        den += ex;
    }
    float r = 1.0f / (den + 1e-16f);
    float v0 = acc0 * r + bias[2 * lane];
    float v1 = acc1 * r + bias[2 * lane + 1];
    v0 = (v0 > 0.f) ? v0 : expm1f(v0);    // ELU
    v1 = (v1 > 0.f) ? v1 : expm1f(v1);
    *reinterpret_cast<float2*>(out + (size_t)wid * 128 + 2 * lane) = make_float2(v0, v1);
}

// Layer 2: F=64, H=1; epilogue adds bias only (mean over 1 head = identity).
__global__ __launch_bounds__(256) void aggregate2(const float* __restrict__ h,
                                                  const float* __restrict__ as,
                                                  const float* __restrict__ ad,
                                                  const int* __restrict__ offs,
                                                  const int* __restrict__ srcs,
                                                  const float* __restrict__ bias,
                                                  float* __restrict__ out, int N) {
    int wid = (blockIdx.x * blockDim.x + threadIdx.x) >> 6;
    int lane = threadIdx.x & 63;
    if (wid >= N) return;
    float adv = ad[wid];
    int e0 = offs[wid], e1 = offs[wid + 1];
    float acc = 0.f, den = 0.f;
    for (int e = e0; e < e1; ++e) {
        int j = srcs[e];
        float t = as[j] + adv;
        t = (t > 0.f) ? t : 0.2f * t;
        float ex = expf(t);
        float hv = h[(size_t)j * 64 + lane];
        acc = fmaf(ex, hv, acc);
        den += ex;
    }
    float r = 1.0f / (den + 1e-16f);
    out[(size_t)wid * 64 + lane] = acc * r + bias[lane];
}

// ---------------- launch ----------------

extern "C" void kernel_launch(void* const* d_in, const int* in_sizes, int n_in,
                              void* d_out, int out_size, void* d_ws, size_t ws_size,
                              hipStream_t stream) {
    const float* x      = (const float*)d_in[0];
    const int*   ei     = (const int*)d_in[1];
    const float* W1     = (const float*)d_in[2];
    const float* a_src1 = (const float*)d_in[3];
    const float* a_dst1 = (const float*)d_in[4];
    const float* b1     = (const float*)d_in[5];
    const float* W2     = (const float*)d_in[6];
    const float* a_src2 = (const float*)d_in[7];
    const float* a_dst2 = (const float*)d_in[8];
    const float* b2     = (const float*)d_in[9];
    float* out = (float*)d_out;

    const int N = out_size / 64;          // 100000
    const int E = in_sizes[1] / 2;        // 1600000
    const int Etot = E + N;

    // workspace carve (256B aligned chunks)
    size_t off = 0;
    auto carve = [&](size_t bytes) -> void* {
        void* p = (char*)d_ws + off;
        off += (bytes + 255) & ~(size_t)255;
        return p;
    };
    float* h1     = (float*)carve((size_t)N * 128 * 4);
    float* hmid   = (float*)carve((size_t)N * 128 * 4);
    float* as1    = (float*)carve((size_t)N * 4 * 4);
    float* ad1    = (float*)carve((size_t)N * 4 * 4);
    float* as2    = (float*)carve((size_t)N * 4);
    float* ad2    = (float*)carve((size_t)N * 4);
    int*   deg    = (int*)carve((size_t)N * 4);
    int*   offs   = (int*)carve((size_t)(N + 1) * 4);
    int*   cursor = (int*)carve((size_t)N * 4);
    int*   srcs   = (int*)carve((size_t)Etot * 4);
    int*   bsum   = (int*)carve(1024 * 4);
    float* h2     = h1;   // alias: h1 dead after aggregate1

    int nb = (N + 1023) / 1024;

    // CSR build (shared by both layers)
    zero_kernel<<<(N + 255) / 256, 256, 0, stream>>>(deg, N);
    hist_kernel<<<(Etot + 255) / 256, 256, 0, stream>>>(ei, E, N, deg);
    scan_bsum<<<nb, 256, 0, stream>>>(deg, bsum, N);
    scan_serial<<<1, 64, 0, stream>>>(bsum, nb);
    scan_final<<<nb, 256, 0, stream>>>(deg, bsum, offs, cursor, N, Etot);
    scatter_kernel<<<(Etot + 255) / 256, 256, 0, stream>>>(ei, E, N, cursor, srcs);

    // Layer 1
    gemm_k128<128><<<(N + 63) / 64, 256, 0, stream>>>(x, W1, h1, N);
    alphas_kernel<4, 32><<<(N + 3) / 4, 256, 0, stream>>>(h1, a_src1, a_dst1, as1, ad1, N);
    aggregate1<<<(N + 3) / 4, 256, 0, stream>>>(h1, as1, ad1, offs, srcs, b1, hmid, N);

    // Layer 2
    gemm_k128<64><<<(N + 63) / 64, 256, 0, stream>>>(hmid, W2, h2, N);
    alphas_kernel<1, 64><<<(N + 3) / 4, 256, 0, stream>>>(h2, a_src2, a_dst2, as2, ad2, N);
    aggregate2<<<(N + 3) / 4, 256, 0, stream>>>(h2, as2, ad2, offs, srcs, b2, out, N);
}

// Round 2
// 579.792 us; speedup vs baseline: 1.3296x; 1.3296x over previous
//
#include <hip/hip_runtime.h>
#include <hip/hip_fp16.h>
#include <math.h>

// GAT 2-layer, N=100000, E=1600000, F_IN=128, HID=128 (H=4,C=32), OUT=64 (H=1,C=64)
// R1 -> R2: store h as fp16 (halves gather bytes), 4-deep unrolled edge loops
// (multiple gathers in flight), __expf. CSR build unchanged.

// ---------------- CSR build ----------------

__global__ void zero_kernel(int* p, int n) {
    int i = blockIdx.x * blockDim.x + threadIdx.x;
    if (i < n) p[i] = 0;
}

__global__ void hist_kernel(const int* __restrict__ ei, int E, int N, int* __restrict__ deg) {
    int k = blockIdx.x * blockDim.x + threadIdx.x;
    int Etot = E + N;
    if (k >= Etot) return;
    int d = (k < E) ? ei[E + k] : (k - E);
    atomicAdd(&deg[d], 1);
}

__global__ void scan_bsum(const int* __restrict__ deg, int* __restrict__ bsum, int N) {
    __shared__ int sdata[256];
    int b = blockIdx.x, t = threadIdx.x;
    int base = b * 1024 + t * 4;
    int s = 0;
#pragma unroll
    for (int i = 0; i < 4; ++i) {
        int idx = base + i;
        if (idx < N) s += deg[idx];
    }
    sdata[t] = s;
    __syncthreads();
    for (int o = 128; o > 0; o >>= 1) {
        if (t < o) sdata[t] += sdata[t + o];
        __syncthreads();
    }
    if (t == 0) bsum[b] = sdata[0];
}

__global__ void scan_serial(int* bsum, int nb) {
    if (blockIdx.x == 0 && threadIdx.x == 0) {
        int run = 0;
        for (int i = 0; i < nb; ++i) { int t = bsum[i]; bsum[i] = run; run += t; }
    }
}

__global__ void scan_final(const int* __restrict__ deg, const int* __restrict__ bsum,
                           int* __restrict__ offs, int* __restrict__ cursor, int N, int Etot) {
    __shared__ int sdata[256];
    int b = blockIdx.x, t = threadIdx.x;
    int base = b * 1024 + t * 4;
    int v[4];
    int sum = 0;
#pragma unroll
    for (int i = 0; i < 4; ++i) {
        int idx = base + i;
        v[i] = (idx < N) ? deg[idx] : 0;
        sum += v[i];
    }
    sdata[t] = sum;
    __syncthreads();
    for (int o = 1; o < 256; o <<= 1) {
        int add = (t >= o) ? sdata[t - o] : 0;
        __syncthreads();
        sdata[t] += add;
        __syncthreads();
    }
    int excl = sdata[t] - sum;
    int run = bsum[b] + excl;
#pragma unroll
    for (int i = 0; i < 4; ++i) {
        int idx = base + i;
        if (idx < N) { offs[idx] = run; cursor[idx] = run; }
        run += v[i];
    }
    if (b == 0 && t == 0) offs[N] = Etot;
}

__global__ void scatter_kernel(const int* __restrict__ ei, int E, int N,
                               int* __restrict__ cursor, int* __restrict__ srcs) {
    int k = blockIdx.x * blockDim.x + threadIdx.x;
    int Etot = E + N;
    if (k >= Etot) return;
    int s, d;
    if (k < E) { s = ei[k]; d = ei[E + k]; } else { s = d = k - E; }
    int pos = atomicAdd(&cursor[d], 1);
    srcs[pos] = s;
}

// ---------------- GEMM: C[M,NC] = A[M,128] * B[128,NC], fp16 or f32 out ----------------

template <int NC, typename OutT>
__global__ __launch_bounds__(256) void gemm_k128(const float* __restrict__ A,
                                                 const float* __restrict__ B,
                                                 OutT* __restrict__ C, int M) {
    constexpr int BM = 64, BK = 32, K = 128;
    constexpr int TPR = NC / 4;          // threads covering NC cols via 4-col groups
    constexpr int R = BM / (256 / TPR);  // rows per thread (8 or 4)
    __shared__ float AsT[BK][BM];
    __shared__ float Bs[BK][NC];
    int tid = threadIdx.x;
    int tx = tid % TPR, ty = tid / TPR;
    int rowBase = blockIdx.x * BM;
    float acc[R][4] = {};
    for (int k0 = 0; k0 < K; k0 += BK) {
#pragma unroll
        for (int i = 0; i < 4; ++i) {
            int lin = tid + i * 256;     // 0..1023 float2 slots
            int row = lin >> 4;          // 16 float2 per row
            int kp = lin & 15;
            int grow = rowBase + row;
            if (grow >= M) grow = M - 1;
            float2 v = *reinterpret_cast<const float2*>(A + (size_t)grow * K + k0 + kp * 2);
            AsT[kp * 2][row] = v.x;
            AsT[kp * 2 + 1][row] = v.y;
        }
#pragma unroll
        for (int i = 0; i < (BK * NC) / 1024; ++i) {
            int lin = tid + i * 256;     // float4 index
            int row = lin / (NC / 4);
            int col4 = lin % (NC / 4);
            float4 v = *reinterpret_cast<const float4*>(B + (size_t)(k0 + row) * NC + col4 * 4);
            *reinterpret_cast<float4*>(&Bs[row][col4 * 4]) = v;
        }
        __syncthreads();
#pragma unroll
        for (int kk = 0; kk < BK; ++kk) {
            float4 bv = *reinterpret_cast<const float4*>(&Bs[kk][tx * 4]);
            float a[R];
#pragma unroll
            for (int r4 = 0; r4 < R; r4 += 4) {
                float4 av = *reinterpret_cast<const float4*>(&AsT[kk][ty * R + r4]);
                a[r4] = av.x; a[r4 + 1] = av.y; a[r4 + 2] = av.z; a[r4 + 3] = av.w;
            }
#pragma unroll
            for (int r = 0; r < R; ++r) {
                acc[r][0] = fmaf(a[r], bv.x, acc[r][0]);
                acc[r][1] = fmaf(a[r], bv.y, acc[r][1]);
                acc[r][2] = fmaf(a[r], bv.z, acc[r][2]);
                acc[r][3] = fmaf(a[r], bv.w, acc[r][3]);
            }
        }
        __syncthreads();
    }
#pragma unroll
    for (int r = 0; r < R; ++r) {
        int grow = rowBase + ty * R + r;
        if (grow < M) {
            if constexpr (sizeof(OutT) == 2) {
                __half2 p0 = __floats2half2_rn(acc[r][0], acc[r][1]);
                __half2 p1 = __floats2half2_rn(acc[r][2], acc[r][3]);
                __half2* cp = reinterpret_cast<__half2*>((__half*)C + (size_t)grow * NC + tx * 4);
                cp[0] = p0;
                cp[1] = p1;
            } else {
                float4 v = make_float4(acc[r][0], acc[r][1], acc[r][2], acc[r][3]);
                *reinterpret_cast<float4*>((float*)C + (size_t)grow * NC + tx * 4) = v;
            }
        }
    }
}

// ---------------- alpha_s / alpha_d (fp16 h) ----------------

// Layer 1: F=128, H=4, C=32. Wave per node, 2 channels/lane.
__global__ __launch_bounds__(256) void alphas1_kernel(const __half* __restrict__ h,
                                                      const float* __restrict__ a_src,
                                                      const float* __restrict__ a_dst,
                                                      float* __restrict__ as,
                                                      float* __restrict__ ad, int N) {
    int wid = (blockIdx.x * blockDim.x + threadIdx.x) >> 6;
    int lane = threadIdx.x & 63;
    if (wid >= N) return;
    const __half2* hp = reinterpret_cast<const __half2*>(h);
    float2 hv = __half22float2(hp[(size_t)wid * 64 + lane]);
    float s = hv.x * a_src[2 * lane] + hv.y * a_src[2 * lane + 1];
    float d = hv.x * a_dst[2 * lane] + hv.y * a_dst[2 * lane + 1];
#pragma unroll
    for (int o = 1; o < 16; o <<= 1) {
        s += __shfl_xor(s, o, 64);
        d += __shfl_xor(d, o, 64);
    }
    if ((lane & 15) == 0) {
        int head = lane >> 4;
        as[(size_t)wid * 4 + head] = s;
        ad[(size_t)wid * 4 + head] = d;
    }
}

// Layer 2: F=64, H=1.
__global__ __launch_bounds__(256) void alphas2_kernel(const __half* __restrict__ h,
                                                      const float* __restrict__ a_src,
                                                      const float* __restrict__ a_dst,
                                                      float* __restrict__ as,
                                                      float* __restrict__ ad, int N) {
    int wid = (blockIdx.x * blockDim.x + threadIdx.x) >> 6;
    int lane = threadIdx.x & 63;
    if (wid >= N) return;
    float hv = __half2float(h[(size_t)wid * 64 + lane]);
    float s = hv * a_src[lane];
    float d = hv * a_dst[lane];
#pragma unroll
    for (int o = 1; o < 64; o <<= 1) {
        s += __shfl_xor(s, o, 64);
        d += __shfl_xor(d, o, 64);
    }
    if (lane == 0) {
        as[wid] = s;
        ad[wid] = d;
    }
}

// ---------------- aggregation (wave per dst node, 4-deep unroll) ----------------

__device__ __forceinline__ float lrelu_exp(float t) {
    t = (t > 0.f) ? t : 0.2f * t;
    return __expf(t);
}

// Layer 1: F=128, H=4, C=32; fused bias + ELU epilogue. h is fp16.
__global__ __launch_bounds__(256) void aggregate1(const __half* __restrict__ h,
                                                  const float* __restrict__ as,
                                                  const float* __restrict__ ad,
                                                  const int* __restrict__ offs,
                                                  const int* __restrict__ srcs,
                                                  const float* __restrict__ bias,
                                                  float* __restrict__ out, int N) {
    int wid = (blockIdx.x * blockDim.x + threadIdx.x) >> 6;
    int lane = threadIdx.x & 63;
    if (wid >= N) return;
    int head = lane >> 4;                 // channels 2*lane, 2*lane+1 -> head = lane/16
    float adv = ad[(size_t)wid * 4 + head];
    int e0 = offs[wid], e1 = offs[wid + 1];
    const __half2* hp = reinterpret_cast<const __half2*>(h);
    float acc0 = 0.f, acc1 = 0.f, den = 0.f;
    int e = e0;
    for (; e + 4 <= e1; e += 4) {
        int j0 = srcs[e], j1 = srcs[e + 1], j2 = srcs[e + 2], j3 = srcs[e + 3];
        float t0 = as[(size_t)j0 * 4 + head] + adv;
        float t1 = as[(size_t)j1 * 4 + head] + adv;
        float t2 = as[(size_t)j2 * 4 + head] + adv;
        float t3 = as[(size_t)j3 * 4 + head] + adv;
        float2 h0 = __half22float2(hp[(size_t)j0 * 64 + lane]);
        float2 h1v = __half22float2(hp[(size_t)j1 * 64 + lane]);
        float2 h2v = __half22float2(hp[(size_t)j2 * 64 + lane]);
        float2 h3v = __half22float2(hp[(size_t)j3 * 64 + lane]);
        float x0 = lrelu_exp(t0), x1 = lrelu_exp(t1), x2 = lrelu_exp(t2), x3 = lrelu_exp(t3);
        acc0 = fmaf(x0, h0.x, acc0); acc1 = fmaf(x0, h0.y, acc1);
        acc0 = fmaf(x1, h1v.x, acc0); acc1 = fmaf(x1, h1v.y, acc1);
        acc0 = fmaf(x2, h2v.x, acc0); acc1 = fmaf(x2, h2v.y, acc1);
        acc0 = fmaf(x3, h3v.x, acc0); acc1 = fmaf(x3, h3v.y, acc1);
        den += (x0 + x1) + (x2 + x3);
    }
    for (; e < e1; ++e) {
        int j = srcs[e];
        float ex = lrelu_exp(as[(size_t)j * 4 + head] + adv);
        float2 hv = __half22float2(hp[(size_t)j * 64 + lane]);
        acc0 = fmaf(ex, hv.x, acc0);
        acc1 = fmaf(ex, hv.y, acc1);
        den += ex;
    }
    float r = 1.0f / (den + 1e-16f);
    float v0 = acc0 * r + bias[2 * lane];
    float v1 = acc1 * r + bias[2 * lane + 1];
    v0 = (v0 > 0.f) ? v0 : expm1f(v0);    // ELU
    v1 = (v1 > 0.f) ? v1 : expm1f(v1);
    *reinterpret_cast<float2*>(out + (size_t)wid * 128 + 2 * lane) = make_float2(v0, v1);
}

// Layer 2: F=64, H=1; bias epilogue. h is fp16.
__global__ __launch_bounds__(256) void aggregate2(const __half* __restrict__ h,
                                                  const float* __restrict__ as,
                                                  const float* __restrict__ ad,
                                                  const int* __restrict__ offs,
                                                  const int* __restrict__ srcs,
                                                  const float* __restrict__ bias,
                                                  float* __restrict__ out, int N) {
    int wid = (blockIdx.x * blockDim.x + threadIdx.x) >> 6;
    int lane = threadIdx.x & 63;
    if (wid >= N) return;
    float adv = ad[wid];
    int e0 = offs[wid], e1 = offs[wid + 1];
    float acc = 0.f, den = 0.f;
    int e = e0;
    for (; e + 4 <= e1; e += 4) {
        int j0 = srcs[e], j1 = srcs[e + 1], j2 = srcs[e + 2], j3 = srcs[e + 3];
        float t0 = as[j0] + adv;
        float t1 = as[j1] + adv;
        float t2 = as[j2] + adv;
        float t3 = as[j3] + adv;
        float h0 = __half2float(h[(size_t)j0 * 64 + lane]);
        float h1v = __half2float(h[(size_t)j1 * 64 + lane]);
        float h2v = __half2float(h[(size_t)j2 * 64 + lane]);
        float h3v = __half2float(h[(size_t)j3 * 64 + lane]);
        float x0 = lrelu_exp(t0), x1 = lrelu_exp(t1), x2 = lrelu_exp(t2), x3 = lrelu_exp(t3);
        acc = fmaf(x0, h0, acc);
        acc = fmaf(x1, h1v, acc);
        acc = fmaf(x2, h2v, acc);
        acc = fmaf(x3, h3v, acc);
        den += (x0 + x1) + (x2 + x3);
    }
    for (; e < e1; ++e) {
        int j = srcs[e];
        float ex = lrelu_exp(as[j] + adv);
        acc = fmaf(ex, __half2float(h[(size_t)j * 64 + lane]), acc);
        den += ex;
    }
    float r = 1.0f / (den + 1e-16f);
    out[(size_t)wid * 64 + lane] = acc * r + bias[lane];
}

// ---------------- launch ----------------

extern "C" void kernel_launch(void* const* d_in, const int* in_sizes, int n_in,
                              void* d_out, int out_size, void* d_ws, size_t ws_size,
                              hipStream_t stream) {
    const float* x      = (const float*)d_in[0];
    const int*   ei     = (const int*)d_in[1];
    const float* W1     = (const float*)d_in[2];
    const float* a_src1 = (const float*)d_in[3];
    const float* a_dst1 = (const float*)d_in[4];
    const float* b1     = (const float*)d_in[5];
    const float* W2     = (const float*)d_in[6];
    const float* a_src2 = (const float*)d_in[7];
    const float* a_dst2 = (const float*)d_in[8];
    const float* b2     = (const float*)d_in[9];
    float* out = (float*)d_out;

    const int N = out_size / 64;          // 100000
    const int E = in_sizes[1] / 2;        // 1600000
    const int Etot = E + N;

    size_t off = 0;
    auto carve = [&](size_t bytes) -> void* {
        void* p = (char*)d_ws + off;
        off += (bytes + 255) & ~(size_t)255;
        return p;
    };
    __half* h1    = (__half*)carve((size_t)N * 128 * 2);   // fp16 h, layer 1
    float* hmid   = (float*)carve((size_t)N * 128 * 4);    // f32 ELU output
    float* as1    = (float*)carve((size_t)N * 4 * 4);
    float* ad1    = (float*)carve((size_t)N * 4 * 4);
    float* as2    = (float*)carve((size_t)N * 4);
    float* ad2    = (float*)carve((size_t)N * 4);
    int*   deg    = (int*)carve((size_t)N * 4);
    int*   offs   = (int*)carve((size_t)(N + 1) * 4);
    int*   cursor = (int*)carve((size_t)N * 4);
    int*   srcs   = (int*)carve((size_t)Etot * 4);
    int*   bsum   = (int*)carve(1024 * 4);
    __half* h2    = h1;    // alias: h1 dead after aggregate1 (12.8 MB < 25.6 MB)

    int nb = (N + 1023) / 1024;

    // CSR build (shared by both layers)
    zero_kernel<<<(N + 255) / 256, 256, 0, stream>>>(deg, N);
    hist_kernel<<<(Etot + 255) / 256, 256, 0, stream>>>(ei, E, N, deg);
    scan_bsum<<<nb, 256, 0, stream>>>(deg, bsum, N);
    scan_serial<<<1, 64, 0, stream>>>(bsum, nb);
    scan_final<<<nb, 256, 0, stream>>>(deg, bsum, offs, cursor, N, Etot);
    scatter_kernel<<<(Etot + 255) / 256, 256, 0, stream>>>(ei, E, N, cursor, srcs);

    // Layer 1
    gemm_k128<128, __half><<<(N + 63) / 64, 256, 0, stream>>>(x, W1, h1, N);
    alphas1_kernel<<<(N + 3) / 4, 256, 0, stream>>>(h1, a_src1, a_dst1, as1, ad1, N);
    aggregate1<<<(N + 3) / 4, 256, 0, stream>>>(h1, as1, ad1, offs, srcs, b1, hmid, N);

    // Layer 2
    gemm_k128<64, __half><<<(N + 63) / 64, 256, 0, stream>>>(hmid, W2, h2, N);
    alphas2_kernel<<<(N + 3) / 4, 256, 0, stream>>>(h2, a_src2, a_dst2, as2, ad2, N);
    aggregate2<<<(N + 3) / 4, 256, 0, stream>>>(h2, as2, ad2, offs, srcs, b2, out, N);
}

// Round 3
// 462.260 us; speedup vs baseline: 1.6677x; 1.2543x over previous
//
#include <hip/hip_runtime.h>
#include <hip/hip_fp16.h>
#include <math.h>

// GAT 2-layer, N=100000, E=1600000, F_IN=128, HID=128 (H=4,C=32), OUT=64 (H=1,C=64)
// R2 -> R3: replace atomic hist+scatter CSR build (1.7M contended atomics, 108MB
// of partial-line writes) with a two-level bucketed counting sort:
//   bucket_hist (LDS hist, ~33K atomics) -> scan_buckets -> bucket_scatter
//   (per-block reserved contiguous runs, line-efficient writes) -> bucket_sort
//   (per-bucket LDS counting sort; scatter stays inside a 35KB L2-hot region).
// Aggregation kernels unchanged from R2 (fp16 h, 4-deep unroll).

#define BSH 9      // log2 dsts per bucket
#define DPB 512    // dsts per bucket
#define NBK 256    // max buckets (covers N < 131072)
#define CH1 16384  // edges per block in bucket_scatter

// ---------------- CSR build: bucketed counting sort ----------------

__global__ void zero_small(unsigned* p) {
    p[threadIdx.x] = 0;   // 1 block x 256
}

__global__ __launch_bounds__(256) void bucket_hist(const int* __restrict__ ei, int E, int N,
                                                   unsigned* __restrict__ bcount) {
    __shared__ unsigned hist[NBK];
    int t = threadIdx.x;
    hist[t] = 0;
    __syncthreads();
    int Etot = E + N;
    for (int k = blockIdx.x * 256 + t; k < Etot; k += gridDim.x * 256) {
        int d = (k < E) ? ei[E + k] : (k - E);
        atomicAdd(&hist[d >> BSH], 1u);
    }
    __syncthreads();
    unsigned c = hist[t];
    if (c) atomicAdd(&bcount[t], c);
}

__global__ void scan_buckets(const unsigned* __restrict__ bcount, unsigned* __restrict__ bbase,
                             unsigned* __restrict__ bcursor) {
    __shared__ unsigned s[NBK];
    int t = threadIdx.x;
    unsigned v = bcount[t];
    s[t] = v;
    __syncthreads();
    for (int o = 1; o < NBK; o <<= 1) {
        unsigned add = (t >= o) ? s[t - o] : 0;
        __syncthreads();
        s[t] += add;
        __syncthreads();
    }
    unsigned excl = s[t] - v;
    bbase[t] = excl;
    bcursor[t] = excl;
    if (t == NBK - 1) bbase[NBK] = excl + v;   // = Etot
}

__global__ __launch_bounds__(256) void bucket_scatter(const int* __restrict__ ei, int E, int N,
                                                      unsigned* __restrict__ bcursor,
                                                      uint2* __restrict__ rec) {
    __shared__ unsigned hist[NBK];
    __shared__ unsigned base[NBK];
    int t = threadIdx.x;
    hist[t] = 0;
    __syncthreads();
    int Etot = E + N;
    int k0 = blockIdx.x * CH1;
    int k1 = min(k0 + CH1, Etot);
    for (int k = k0 + t; k < k1; k += 256) {
        int d = (k < E) ? ei[E + k] : (k - E);
        atomicAdd(&hist[d >> BSH], 1u);
    }
    __syncthreads();
    unsigned c = hist[t];
    base[t] = c ? atomicAdd(&bcursor[t], c) : 0u;
    hist[t] = 0;
    __syncthreads();
    for (int k = k0 + t; k < k1; k += 256) {
        int s, d;
        if (k < E) { s = ei[k]; d = ei[E + k]; } else { s = d = k - E; }
        int b = d >> BSH;
        unsigned r = atomicAdd(&hist[b], 1u);
        rec[base[b] + r] = make_uint2((unsigned)s, (unsigned)d);
    }
}

__global__ __launch_bounds__(256) void bucket_sort(const uint2* __restrict__ rec,
                                                   const unsigned* __restrict__ bbase,
                                                   int* __restrict__ offs, int* __restrict__ srcs,
                                                   int N, int Etot) {
    __shared__ unsigned hist[DPB];
    __shared__ unsigned tsum[256];
    int t = threadIdx.x, bb = blockIdx.x;
    unsigned r0 = bbase[bb], r1 = bbase[bb + 1];
    hist[t] = 0;
    hist[t + 256] = 0;
    __syncthreads();
    int dlo = bb << BSH;
    for (unsigned k = r0 + t; k < r1; k += 256) {
        uint2 e = rec[k];
        atomicAdd(&hist[e.y - dlo], 1u);
    }
    __syncthreads();
    unsigned h0 = hist[2 * t], h1 = hist[2 * t + 1];
    tsum[t] = h0 + h1;
    __syncthreads();
    for (int o = 1; o < 256; o <<= 1) {
        unsigned a = (t >= o) ? tsum[t - o] : 0;
        __syncthreads();
        tsum[t] += a;
        __syncthreads();
    }
    unsigned tb = tsum[t] - (h0 + h1);
    int d0 = dlo + 2 * t;
    if (d0 < N) offs[d0] = (int)(r0 + tb);
    if (d0 + 1 < N) offs[d0 + 1] = (int)(r0 + tb + h0);
    hist[2 * t] = tb;            // reuse as relative cursors
    hist[2 * t + 1] = tb + h0;
    __syncthreads();
    for (unsigned k = r0 + t; k < r1; k += 256) {
        uint2 e = rec[k];
        unsigned r = atomicAdd(&hist[e.y - dlo], 1u);
        srcs[r0 + r] = (int)e.x;
    }
    if (bb == 0 && t == 0) offs[N] = Etot;
}

// ---------------- GEMM: C[M,NC] = A[M,128] * B[128,NC], fp16 or f32 out ----------------

template <int NC, typename OutT>
__global__ __launch_bounds__(256) void gemm_k128(const float* __restrict__ A,
                                                 const float* __restrict__ B,
                                                 OutT* __restrict__ C, int M) {
    constexpr int BM = 64, BK = 32, K = 128;
    constexpr int TPR = NC / 4;          // threads covering NC cols via 4-col groups
    constexpr int R = BM / (256 / TPR);  // rows per thread (8 or 4)
    __shared__ float AsT[BK][BM];
    __shared__ float Bs[BK][NC];
    int tid = threadIdx.x;
    int tx = tid % TPR, ty = tid / TPR;
    int rowBase = blockIdx.x * BM;
    float acc[R][4] = {};
    for (int k0 = 0; k0 < K; k0 += BK) {
#pragma unroll
        for (int i = 0; i < 4; ++i) {
            int lin = tid + i * 256;     // 0..1023 float2 slots
            int row = lin >> 4;          // 16 float2 per row
            int kp = lin & 15;
            int grow = rowBase + row;
            if (grow >= M) grow = M - 1;
            float2 v = *reinterpret_cast<const float2*>(A + (size_t)grow * K + k0 + kp * 2);
            AsT[kp * 2][row] = v.x;
            AsT[kp * 2 + 1][row] = v.y;
        }
#pragma unroll
        for (int i = 0; i < (BK * NC) / 1024; ++i) {
            int lin = tid + i * 256;     // float4 index
            int row = lin / (NC / 4);
            int col4 = lin % (NC / 4);
            float4 v = *reinterpret_cast<const float4*>(B + (size_t)(k0 + row) * NC + col4 * 4);
            *reinterpret_cast<float4*>(&Bs[row][col4 * 4]) = v;
        }
        __syncthreads();
#pragma unroll
        for (int kk = 0; kk < BK; ++kk) {
            float4 bv = *reinterpret_cast<const float4*>(&Bs[kk][tx * 4]);
            float a[R];
#pragma unroll
            for (int r4 = 0; r4 < R; r4 += 4) {
                float4 av = *reinterpret_cast<const float4*>(&AsT[kk][ty * R + r4]);
                a[r4] = av.x; a[r4 + 1] = av.y; a[r4 + 2] = av.z; a[r4 + 3] = av.w;
            }
#pragma unroll
            for (int r = 0; r < R; ++r) {
                acc[r][0] = fmaf(a[r], bv.x, acc[r][0]);
                acc[r][1] = fmaf(a[r], bv.y, acc[r][1]);
                acc[r][2] = fmaf(a[r], bv.z, acc[r][2]);
                acc[r][3] = fmaf(a[r], bv.w, acc[r][3]);
            }
        }
        __syncthreads();
    }
#pragma unroll
    for (int r = 0; r < R; ++r) {
        int grow = rowBase + ty * R + r;
        if (grow < M) {
            if constexpr (sizeof(OutT) == 2) {
                __half2 p0 = __floats2half2_rn(acc[r][0], acc[r][1]);
                __half2 p1 = __floats2half2_rn(acc[r][2], acc[r][3]);
                __half2* cp = reinterpret_cast<__half2*>((__half*)C + (size_t)grow * NC + tx * 4);
                cp[0] = p0;
                cp[1] = p1;
            } else {
                float4 v = make_float4(acc[r][0], acc[r][1], acc[r][2], acc[r][3]);
                *reinterpret_cast<float4*>((float*)C + (size_t)grow * NC + tx * 4) = v;
            }
        }
    }
}

// ---------------- alpha_s / alpha_d (fp16 h) ----------------

__global__ __launch_bounds__(256) void alphas1_kernel(const __half* __restrict__ h,
                                                      const float* __restrict__ a_src,
                                                      const float* __restrict__ a_dst,
                                                      float* __restrict__ as,
                                                      float* __restrict__ ad, int N) {
    int wid = (blockIdx.x * blockDim.x + threadIdx.x) >> 6;
    int lane = threadIdx.x & 63;
    if (wid >= N) return;
    const __half2* hp = reinterpret_cast<const __half2*>(h);
    float2 hv = __half22float2(hp[(size_t)wid * 64 + lane]);
    float s = hv.x * a_src[2 * lane] + hv.y * a_src[2 * lane + 1];
    float d = hv.x * a_dst[2 * lane] + hv.y * a_dst[2 * lane + 1];
#pragma unroll
    for (int o = 1; o < 16; o <<= 1) {
        s += __shfl_xor(s, o, 64);
        d += __shfl_xor(d, o, 64);
    }
    if ((lane & 15) == 0) {
        int head = lane >> 4;
        as[(size_t)wid * 4 + head] = s;
        ad[(size_t)wid * 4 + head] = d;
    }
}

__global__ __launch_bounds__(256) void alphas2_kernel(const __half* __restrict__ h,
                                                      const float* __restrict__ a_src,
                                                      const float* __restrict__ a_dst,
                                                      float* __restrict__ as,
                                                      float* __restrict__ ad, int N) {
    int wid = (blockIdx.x * blockDim.x + threadIdx.x) >> 6;
    int lane = threadIdx.x & 63;
    if (wid >= N) return;
    float hv = __half2float(h[(size_t)wid * 64 + lane]);
    float s = hv * a_src[lane];
    float d = hv * a_dst[lane];
#pragma unroll
    for (int o = 1; o < 64; o <<= 1) {
        s += __shfl_xor(s, o, 64);
        d += __shfl_xor(d, o, 64);
    }
    if (lane == 0) {
        as[wid] = s;
        ad[wid] = d;
    }
}

// ---------------- aggregation (wave per dst node, 4-deep unroll) ----------------

__device__ __forceinline__ float lrelu_exp(float t) {
    t = (t > 0.f) ? t : 0.2f * t;
    return __expf(t);
}

__global__ __launch_bounds__(256) void aggregate1(const __half* __restrict__ h,
                                                  const float* __restrict__ as,
                                                  const float* __restrict__ ad,
                                                  const int* __restrict__ offs,
                                                  const int* __restrict__ srcs,
                                                  const float* __restrict__ bias,
                                                  float* __restrict__ out, int N) {
    int wid = (blockIdx.x * blockDim.x + threadIdx.x) >> 6;
    int lane = threadIdx.x & 63;
    if (wid >= N) return;
    int head = lane >> 4;
    float adv = ad[(size_t)wid * 4 + head];
    int e0 = offs[wid], e1 = offs[wid + 1];
    const __half2* hp = reinterpret_cast<const __half2*>(h);
    float acc0 = 0.f, acc1 = 0.f, den = 0.f;
    int e = e0;
    for (; e + 4 <= e1; e += 4) {
        int j0 = srcs[e], j1 = srcs[e + 1], j2 = srcs[e + 2], j3 = srcs[e + 3];
        float t0 = as[(size_t)j0 * 4 + head] + adv;
        float t1 = as[(size_t)j1 * 4 + head] + adv;
        float t2 = as[(size_t)j2 * 4 + head] + adv;
        float t3 = as[(size_t)j3 * 4 + head] + adv;
        float2 h0 = __half22float2(hp[(size_t)j0 * 64 + lane]);
        float2 h1v = __half22float2(hp[(size_t)j1 * 64 + lane]);
        float2 h2v = __half22float2(hp[(size_t)j2 * 64 + lane]);
        float2 h3v = __half22float2(hp[(size_t)j3 * 64 + lane]);
        float x0 = lrelu_exp(t0), x1 = lrelu_exp(t1), x2 = lrelu_exp(t2), x3 = lrelu_exp(t3);
        acc0 = fmaf(x0, h0.x, acc0); acc1 = fmaf(x0, h0.y, acc1);
        acc0 = fmaf(x1, h1v.x, acc0); acc1 = fmaf(x1, h1v.y, acc1);
        acc0 = fmaf(x2, h2v.x, acc0); acc1 = fmaf(x2, h2v.y, acc1);
        acc0 = fmaf(x3, h3v.x, acc0); acc1 = fmaf(x3, h3v.y, acc1);
        den += (x0 + x1) + (x2 + x3);
    }
    for (; e < e1; ++e) {
        int j = srcs[e];
        float ex = lrelu_exp(as[(size_t)j * 4 + head] + adv);
        float2 hv = __half22float2(hp[(size_t)j * 64 + lane]);
        acc0 = fmaf(ex, hv.x, acc0);
        acc1 = fmaf(ex, hv.y, acc1);
        den += ex;
    }
    float r = 1.0f / (den + 1e-16f);
    float v0 = acc0 * r + bias[2 * lane];
    float v1 = acc1 * r + bias[2 * lane + 1];
    v0 = (v0 > 0.f) ? v0 : expm1f(v0);    // ELU
    v1 = (v1 > 0.f) ? v1 : expm1f(v1);
    *reinterpret_cast<float2*>(out + (size_t)wid * 128 + 2 * lane) = make_float2(v0, v1);
}

__global__ __launch_bounds__(256) void aggregate2(const __half* __restrict__ h,
                                                  const float* __restrict__ as,
                                                  const float* __restrict__ ad,
                                                  const int* __restrict__ offs,
                                                  const int* __restrict__ srcs,
                                                  const float* __restrict__ bias,
                                                  float* __restrict__ out, int N) {
    int wid = (blockIdx.x * blockDim.x + threadIdx.x) >> 6;
    int lane = threadIdx.x & 63;
    if (wid >= N) return;
    float adv = ad[wid];
    int e0 = offs[wid], e1 = offs[wid + 1];
    float acc = 0.f, den = 0.f;
    int e = e0;
    for (; e + 4 <= e1; e += 4) {
        int j0 = srcs[e], j1 = srcs[e + 1], j2 = srcs[e + 2], j3 = srcs[e + 3];
        float t0 = as[j0] + adv;
        float t1 = as[j1] + adv;
        float t2 = as[j2] + adv;
        float t3 = as[j3] + adv;
        float h0 = __half2float(h[(size_t)j0 * 64 + lane]);
        float h1v = __half2float(h[(size_t)j1 * 64 + lane]);
        float h2v = __half2float(h[(size_t)j2 * 64 + lane]);
        float h3v = __half2float(h[(size_t)j3 * 64 + lane]);
        float x0 = lrelu_exp(t0), x1 = lrelu_exp(t1), x2 = lrelu_exp(t2), x3 = lrelu_exp(t3);
        acc = fmaf(x0, h0, acc);
        acc = fmaf(x1, h1v, acc);
        acc = fmaf(x2, h2v, acc);
        acc = fmaf(x3, h3v, acc);
        den += (x0 + x1) + (x2 + x3);
    }
    for (; e < e1; ++e) {
        int j = srcs[e];
        float ex = lrelu_exp(as[j] + adv);
        acc = fmaf(ex, __half2float(h[(size_t)j * 64 + lane]), acc);
        den += ex;
    }
    float r = 1.0f / (den + 1e-16f);
    out[(size_t)wid * 64 + lane] = acc * r + bias[lane];
}

// ---------------- launch ----------------

extern "C" void kernel_launch(void* const* d_in, const int* in_sizes, int n_in,
                              void* d_out, int out_size, void* d_ws, size_t ws_size,
                              hipStream_t stream) {
    const float* x      = (const float*)d_in[0];
    const int*   ei     = (const int*)d_in[1];
    const float* W1     = (const float*)d_in[2];
    const float* a_src1 = (const float*)d_in[3];
    const float* a_dst1 = (const float*)d_in[4];
    const float* b1     = (const float*)d_in[5];
    const float* W2     = (const float*)d_in[6];
    const float* a_src2 = (const float*)d_in[7];
    const float* a_dst2 = (const float*)d_in[8];
    const float* b2     = (const float*)d_in[9];
    float* out = (float*)d_out;

    const int N = out_size / 64;          // 100000
    const int E = in_sizes[1] / 2;        // 1600000
    const int Etot = E + N;

    size_t off = 0;
    auto carve = [&](size_t bytes) -> void* {
        void* p = (char*)d_ws + off;
        off += (bytes + 255) & ~(size_t)255;
        return p;
    };
    __half* h1      = (__half*)carve((size_t)N * 128 * 2);   // fp16 h, layer 1
    float* hmid     = (float*)carve((size_t)N * 128 * 4);    // f32 ELU output
    float* as1      = (float*)carve((size_t)N * 4 * 4);
    float* ad1      = (float*)carve((size_t)N * 4 * 4);
    float* as2      = (float*)carve((size_t)N * 4);
    float* ad2      = (float*)carve((size_t)N * 4);
    int*   offs     = (int*)carve((size_t)(N + 1) * 4);
    int*   srcs     = (int*)carve((size_t)Etot * 4);
    uint2* rec      = (uint2*)carve((size_t)Etot * 8);
    unsigned* bcount  = (unsigned*)carve(NBK * 4);
    unsigned* bbase   = (unsigned*)carve((NBK + 1) * 4);
    unsigned* bcursor = (unsigned*)carve(NBK * 4);
    __half* h2      = h1;    // alias: h1 dead after aggregate1

    // CSR build via bucketed counting sort (shared by both layers)
    zero_small<<<1, 256, 0, stream>>>(bcount);
    bucket_hist<<<128, 256, 0, stream>>>(ei, E, N, bcount);
    scan_buckets<<<1, 256, 0, stream>>>(bcount, bbase, bcursor);
    bucket_scatter<<<(Etot + CH1 - 1) / CH1, 256, 0, stream>>>(ei, E, N, bcursor, rec);
    bucket_sort<<<(N + DPB - 1) / DPB, 256, 0, stream>>>(rec, bbase, offs, srcs, N, Etot);

    // Layer 1
    gemm_k128<128, __half><<<(N + 63) / 64, 256, 0, stream>>>(x, W1, h1, N);
    alphas1_kernel<<<(N + 3) / 4, 256, 0, stream>>>(h1, a_src1, a_dst1, as1, ad1, N);
    aggregate1<<<(N + 3) / 4, 256, 0, stream>>>(h1, as1, ad1, offs, srcs, b1, hmid, N);

    // Layer 2
    gemm_k128<64, __half><<<(N + 63) / 64, 256, 0, stream>>>(hmid, W2, h2, N);
    alphas2_kernel<<<(N + 3) / 4, 256, 0, stream>>>(h2, a_src2, a_dst2, as2, ad2, N);
    aggregate2<<<(N + 3) / 4, 256, 0, stream>>>(h2, as2, ad2, offs, srcs, b2, out, N);
}

// Round 4
// 436.198 us; speedup vs baseline: 1.7673x; 1.0597x over previous
//
#include <hip/hip_runtime.h>
#include <hip/hip_fp16.h>
#include <math.h>

// GAT 2-layer, N=100000, E=1600000, F_IN=128, HID=128 (H=4,C=32), OUT=64 (H=1,C=64)
// R3 -> R4: (1) GEMM A-tile LDS padding [BM+4] kills the 16-way bank conflict
// on the transpose store (stride 64 words ≡ 0 mod 32 banks -> all lanes same
// bank). (2) hmid kept fp16 end-to-end (aggregate1 writes half2, gemm2 reads
// fp16 A). (3) aggregates: 8-deep unroll, lrelu = max(t,0.2t), log2(e) folded
// into as/ad so inner loop is a raw v_exp.

#define BSH 9      // log2 dsts per bucket
#define DPB 512    // dsts per bucket
#define NBK 256    // max buckets (covers N < 131072)
#define CH1 16384  // edges per block in bucket_scatter

__device__ __forceinline__ float exp2_fast(float x) {
#if __has_builtin(__builtin_amdgcn_exp2f)
    return __builtin_amdgcn_exp2f(x);
#else
    return exp2f(x);
#endif
}

// ---------------- CSR build: bucketed counting sort ----------------

__global__ void zero_small(unsigned* p) {
    p[threadIdx.x] = 0;   // 1 block x 256
}

__global__ __launch_bounds__(256) void bucket_hist(const int* __restrict__ ei, int E, int N,
                                                   unsigned* __restrict__ bcount) {
    __shared__ unsigned hist[NBK];
    int t = threadIdx.x;
    hist[t] = 0;
    __syncthreads();
    int Etot = E + N;
    for (int k = blockIdx.x * 256 + t; k < Etot; k += gridDim.x * 256) {
        int d = (k < E) ? ei[E + k] : (k - E);
        atomicAdd(&hist[d >> BSH], 1u);
    }
    __syncthreads();
    unsigned c = hist[t];
    if (c) atomicAdd(&bcount[t], c);
}

__global__ void scan_buckets(const unsigned* __restrict__ bcount, unsigned* __restrict__ bbase,
                             unsigned* __restrict__ bcursor) {
    __shared__ unsigned s[NBK];
    int t = threadIdx.x;
    unsigned v = bcount[t];
    s[t] = v;
    __syncthreads();
    for (int o = 1; o < NBK; o <<= 1) {
        unsigned add = (t >= o) ? s[t - o] : 0;
        __syncthreads();
        s[t] += add;
        __syncthreads();
    }
    unsigned excl = s[t] - v;
    bbase[t] = excl;
    bcursor[t] = excl;
    if (t == NBK - 1) bbase[NBK] = excl + v;   // = Etot
}

__global__ __launch_bounds__(256) void bucket_scatter(const int* __restrict__ ei, int E, int N,
                                                      unsigned* __restrict__ bcursor,
                                                      uint2* __restrict__ rec) {
    __shared__ unsigned hist[NBK];
    __shared__ unsigned base[NBK];
    int t = threadIdx.x;
    hist[t] = 0;
    __syncthreads();
    int Etot = E + N;
    int k0 = blockIdx.x * CH1;
    int k1 = min(k0 + CH1, Etot);
    for (int k = k0 + t; k < k1; k += 256) {
        int d = (k < E) ? ei[E + k] : (k - E);
        atomicAdd(&hist[d >> BSH], 1u);
    }
    __syncthreads();
    unsigned c = hist[t];
    base[t] = c ? atomicAdd(&bcursor[t], c) : 0u;
    hist[t] = 0;
    __syncthreads();
    for (int k = k0 + t; k < k1; k += 256) {
        int s, d;
        if (k < E) { s = ei[k]; d = ei[E + k]; } else { s = d = k - E; }
        int b = d >> BSH;
        unsigned r = atomicAdd(&hist[b], 1u);
        rec[base[b] + r] = make_uint2((unsigned)s, (unsigned)d);
    }
}

__global__ __launch_bounds__(256) void bucket_sort(const uint2* __restrict__ rec,
                                                   const unsigned* __restrict__ bbase,
                                                   int* __restrict__ offs, int* __restrict__ srcs,
                                                   int N, int Etot) {
    __shared__ unsigned hist[DPB];
    __shared__ unsigned tsum[256];
    int t = threadIdx.x, bb = blockIdx.x;
    unsigned r0 = bbase[bb], r1 = bbase[bb + 1];
    hist[t] = 0;
    hist[t + 256] = 0;
    __syncthreads();
    int dlo = bb << BSH;
    for (unsigned k = r0 + t; k < r1; k += 256) {
        uint2 e = rec[k];
        atomicAdd(&hist[e.y - dlo], 1u);
    }
    __syncthreads();
    unsigned h0 = hist[2 * t], h1 = hist[2 * t + 1];
    tsum[t] = h0 + h1;
    __syncthreads();
    for (int o = 1; o < 256; o <<= 1) {
        unsigned a = (t >= o) ? tsum[t - o] : 0;
        __syncthreads();
        tsum[t] += a;
        __syncthreads();
    }
    unsigned tb = tsum[t] - (h0 + h1);
    int d0 = dlo + 2 * t;
    if (d0 < N) offs[d0] = (int)(r0 + tb);
    if (d0 + 1 < N) offs[d0 + 1] = (int)(r0 + tb + h0);
    hist[2 * t] = tb;            // reuse as relative cursors
    hist[2 * t + 1] = tb + h0;
    __syncthreads();
    for (unsigned k = r0 + t; k < r1; k += 256) {
        uint2 e = rec[k];
        unsigned r = atomicAdd(&hist[e.y - dlo], 1u);
        srcs[r0 + r] = (int)e.x;
    }
    if (bb == 0 && t == 0) offs[N] = Etot;
}

// ---------------- GEMM: C[M,NC] = A[M,128] * B[128,NC] ----------------
// InT: float or __half (A). OutT: float or __half (C).

template <int NC, typename InT, typename OutT>
__global__ __launch_bounds__(256) void gemm_k128(const InT* __restrict__ A,
                                                 const float* __restrict__ B,
                                                 OutT* __restrict__ C, int M) {
    constexpr int BM = 64, BK = 32, K = 128;
    constexpr int TPR = NC / 4;          // threads covering NC cols via 4-col groups
    constexpr int R = BM / (256 / TPR);  // rows per thread (8 or 4)
    __shared__ float AsT[BK][BM + 4];    // +4 pad: stride 68 words, breaks 16-way bank conflict
    __shared__ float Bs[BK][NC];
    int tid = threadIdx.x;
    int tx = tid % TPR, ty = tid / TPR;
    int rowBase = blockIdx.x * BM;
    float acc[R][4] = {};
    for (int k0 = 0; k0 < K; k0 += BK) {
#pragma unroll
        for (int i = 0; i < 4; ++i) {
            int lin = tid + i * 256;     // 0..1023 2-elem slots
            int row = lin >> 4;          // 16 slots per row
            int kp = lin & 15;
            int grow = rowBase + row;
            if (grow >= M) grow = M - 1;
            float2 v;
            if constexpr (sizeof(InT) == 2) {
                __half2 hv = *reinterpret_cast<const __half2*>((const __half*)A + (size_t)grow * K + k0 + kp * 2);
                v = __half22float2(hv);
            } else {
                v = *reinterpret_cast<const float2*>((const float*)A + (size_t)grow * K + k0 + kp * 2);
            }
            AsT[kp * 2][row] = v.x;
            AsT[kp * 2 + 1][row] = v.y;
        }
#pragma unroll
        for (int i = 0; i < (BK * NC) / 1024; ++i) {
            int lin = tid + i * 256;     // float4 index
            int row = lin / (NC / 4);
            int col4 = lin % (NC / 4);
            float4 v = *reinterpret_cast<const float4*>(B + (size_t)(k0 + row) * NC + col4 * 4);
            *reinterpret_cast<float4*>(&Bs[row][col4 * 4]) = v;
        }
        __syncthreads();
#pragma unroll
        for (int kk = 0; kk < BK; ++kk) {
            float4 bv = *reinterpret_cast<const float4*>(&Bs[kk][tx * 4]);
            float a[R];
#pragma unroll
            for (int r4 = 0; r4 < R; r4 += 4) {
                float4 av = *reinterpret_cast<const float4*>(&AsT[kk][ty * R + r4]);
                a[r4] = av.x; a[r4 + 1] = av.y; a[r4 + 2] = av.z; a[r4 + 3] = av.w;
            }
#pragma unroll
            for (int r = 0; r < R; ++r) {
                acc[r][0] = fmaf(a[r], bv.x, acc[r][0]);
                acc[r][1] = fmaf(a[r], bv.y, acc[r][1]);
                acc[r][2] = fmaf(a[r], bv.z, acc[r][2]);
                acc[r][3] = fmaf(a[r], bv.w, acc[r][3]);
            }
        }
        __syncthreads();
    }
#pragma unroll
    for (int r = 0; r < R; ++r) {
        int grow = rowBase + ty * R + r;
        if (grow < M) {
            if constexpr (sizeof(OutT) == 2) {
                __half2 p0 = __floats2half2_rn(acc[r][0], acc[r][1]);
                __half2 p1 = __floats2half2_rn(acc[r][2], acc[r][3]);
                __half2* cp = reinterpret_cast<__half2*>((__half*)C + (size_t)grow * NC + tx * 4);
                cp[0] = p0;
                cp[1] = p1;
            } else {
                float4 v = make_float4(acc[r][0], acc[r][1], acc[r][2], acc[r][3]);
                *reinterpret_cast<float4*>((float*)C + (size_t)grow * NC + tx * 4) = v;
            }
        }
    }
}

// ---------------- alpha_s / alpha_d (fp16 h); outputs pre-scaled by log2(e) ----------------

#define LOG2E 1.44269504088896f

__global__ __launch_bounds__(256) void alphas1_kernel(const __half* __restrict__ h,
                                                      const float* __restrict__ a_src,
                                                      const float* __restrict__ a_dst,
                                                      float* __restrict__ as,
                                                      float* __restrict__ ad, int N) {
    int wid = (blockIdx.x * blockDim.x + threadIdx.x) >> 6;
    int lane = threadIdx.x & 63;
    if (wid >= N) return;
    const __half2* hp = reinterpret_cast<const __half2*>(h);
    float2 hv = __half22float2(hp[(size_t)wid * 64 + lane]);
    float s = hv.x * a_src[2 * lane] + hv.y * a_src[2 * lane + 1];
    float d = hv.x * a_dst[2 * lane] + hv.y * a_dst[2 * lane + 1];
#pragma unroll
    for (int o = 1; o < 16; o <<= 1) {
        s += __shfl_xor(s, o, 64);
        d += __shfl_xor(d, o, 64);
    }
    if ((lane & 15) == 0) {
        int head = lane >> 4;
        as[(size_t)wid * 4 + head] = s * LOG2E;
        ad[(size_t)wid * 4 + head] = d * LOG2E;
    }
}

__global__ __launch_bounds__(256) void alphas2_kernel(const __half* __restrict__ h,
                                                      const float* __restrict__ a_src,
                                                      const float* __restrict__ a_dst,
                                                      float* __restrict__ as,
                                                      float* __restrict__ ad, int N) {
    int wid = (blockIdx.x * blockDim.x + threadIdx.x) >> 6;
    int lane = threadIdx.x & 63;
    if (wid >= N) return;
    float hv = __half2float(h[(size_t)wid * 64 + lane]);
    float s = hv * a_src[lane];
    float d = hv * a_dst[lane];
#pragma unroll
    for (int o = 1; o < 64; o <<= 1) {
        s += __shfl_xor(s, o, 64);
        d += __shfl_xor(d, o, 64);
    }
    if (lane == 0) {
        as[wid] = s * LOG2E;
        ad[wid] = d * LOG2E;
    }
}

// ---------------- aggregation (wave per dst node, 8-deep unroll) ----------------
// t is already in log2 domain; lrelu(t)=max(t,0.2t) commutes with the positive scale.

__global__ __launch_bounds__(256) void aggregate1(const __half* __restrict__ h,
                                                  const float* __restrict__ as,
                                                  const float* __restrict__ ad,
                                                  const int* __restrict__ offs,
                                                  const int* __restrict__ srcs,
                                                  const float* __restrict__ bias,
                                                  __half* __restrict__ out, int N) {
    int wid = (blockIdx.x * blockDim.x + threadIdx.x) >> 6;
    int lane = threadIdx.x & 63;
    if (wid >= N) return;
    int head = lane >> 4;
    float adv = ad[(size_t)wid * 4 + head];
    int e0 = offs[wid], e1 = offs[wid + 1];
    const __half2* hp = reinterpret_cast<const __half2*>(h);
    float acc0 = 0.f, acc1 = 0.f, den = 0.f;
    int e = e0;
    for (; e + 8 <= e1; e += 8) {
        int j[8]; float t[8]; __half2 hh[8];
#pragma unroll
        for (int u = 0; u < 8; ++u) j[u] = srcs[e + u];
#pragma unroll
        for (int u = 0; u < 8; ++u) t[u] = as[(size_t)j[u] * 4 + head] + adv;
#pragma unroll
        for (int u = 0; u < 8; ++u) hh[u] = hp[(size_t)j[u] * 64 + lane];
#pragma unroll
        for (int u = 0; u < 8; ++u) {
            float x = exp2_fast(fmaxf(t[u], 0.2f * t[u]));
            float2 hv = __half22float2(hh[u]);
            acc0 = fmaf(x, hv.x, acc0);
            acc1 = fmaf(x, hv.y, acc1);
            den += x;
        }
    }
    for (; e < e1; ++e) {
        int j = srcs[e];
        float t = as[(size_t)j * 4 + head] + adv;
        float x = exp2_fast(fmaxf(t, 0.2f * t));
        float2 hv = __half22float2(hp[(size_t)j * 64 + lane]);
        acc0 = fmaf(x, hv.x, acc0);
        acc1 = fmaf(x, hv.y, acc1);
        den += x;
    }
    float r = 1.0f / (den + 1e-16f);
    float v0 = acc0 * r + bias[2 * lane];
    float v1 = acc1 * r + bias[2 * lane + 1];
    v0 = (v0 > 0.f) ? v0 : expm1f(v0);    // ELU
    v1 = (v1 > 0.f) ? v1 : expm1f(v1);
    reinterpret_cast<__half2*>(out)[(size_t)wid * 64 + lane] = __floats2half2_rn(v0, v1);
}

__global__ __launch_bounds__(256) void aggregate2(const __half* __restrict__ h,
                                                  const float* __restrict__ as,
                                                  const float* __restrict__ ad,
                                                  const int* __restrict__ offs,
                                                  const int* __restrict__ srcs,
                                                  const float* __restrict__ bias,
                                                  float* __restrict__ out, int N) {
    int wid = (blockIdx.x * blockDim.x + threadIdx.x) >> 6;
    int lane = threadIdx.x & 63;
    if (wid >= N) return;
    float adv = ad[wid];
    int e0 = offs[wid], e1 = offs[wid + 1];
    float acc = 0.f, den = 0.f;
    int e = e0;
    for (; e + 8 <= e1; e += 8) {
        int j[8]; float t[8]; __half hh[8];
#pragma unroll
        for (int u = 0; u < 8; ++u) j[u] = srcs[e + u];
#pragma unroll
        for (int u = 0; u < 8; ++u) t[u] = as[j[u]] + adv;
#pragma unroll
        for (int u = 0; u < 8; ++u) hh[u] = h[(size_t)j[u] * 64 + lane];
#pragma unroll
        for (int u = 0; u < 8; ++u) {
            float x = exp2_fast(fmaxf(t[u], 0.2f * t[u]));
            acc = fmaf(x, __half2float(hh[u]), acc);
            den += x;
        }
    }
    for (; e < e1; ++e) {
        int j = srcs[e];
        float t = as[j] + adv;
        float x = exp2_fast(fmaxf(t, 0.2f * t));
        acc = fmaf(x, __half2float(h[(size_t)j * 64 + lane]), acc);
        den += x;
    }
    float r = 1.0f / (den + 1e-16f);
    out[(size_t)wid * 64 + lane] = acc * r + bias[lane];
}

// ---------------- launch ----------------

extern "C" void kernel_launch(void* const* d_in, const int* in_sizes, int n_in,
                              void* d_out, int out_size, void* d_ws, size_t ws_size,
                              hipStream_t stream) {
    const float* x      = (const float*)d_in[0];
    const int*   ei     = (const int*)d_in[1];
    const float* W1     = (const float*)d_in[2];
    const float* a_src1 = (const float*)d_in[3];
    const float* a_dst1 = (const float*)d_in[4];
    const float* b1     = (const float*)d_in[5];
    const float* W2     = (const float*)d_in[6];
    const float* a_src2 = (const float*)d_in[7];
    const float* a_dst2 = (const float*)d_in[8];
    const float* b2     = (const float*)d_in[9];
    float* out = (float*)d_out;

    const int N = out_size / 64;          // 100000
    const int E = in_sizes[1] / 2;        // 1600000
    const int Etot = E + N;

    size_t off = 0;
    auto carve = [&](size_t bytes) -> void* {
        void* p = (char*)d_ws + off;
        off += (bytes + 255) & ~(size_t)255;
        return p;
    };
    __half* h1      = (__half*)carve((size_t)N * 128 * 2);   // fp16 h, layer 1
    __half* hmid    = (__half*)carve((size_t)N * 128 * 2);   // fp16 ELU output
    float* as1      = (float*)carve((size_t)N * 4 * 4);
    float* ad1      = (float*)carve((size_t)N * 4 * 4);
    float* as2      = (float*)carve((size_t)N * 4);
    float* ad2      = (float*)carve((size_t)N * 4);
    int*   offs     = (int*)carve((size_t)(N + 1) * 4);
    int*   srcs     = (int*)carve((size_t)Etot * 4);
    uint2* rec      = (uint2*)carve((size_t)Etot * 8);
    unsigned* bcount  = (unsigned*)carve(NBK * 4);
    unsigned* bbase   = (unsigned*)carve((NBK + 1) * 4);
    unsigned* bcursor = (unsigned*)carve(NBK * 4);
    __half* h2      = h1;    // alias: h1 dead after aggregate1

    // CSR build via bucketed counting sort (shared by both layers)
    zero_small<<<1, 256, 0, stream>>>(bcount);
    bucket_hist<<<128, 256, 0, stream>>>(ei, E, N, bcount);
    scan_buckets<<<1, 256, 0, stream>>>(bcount, bbase, bcursor);
    bucket_scatter<<<(Etot + CH1 - 1) / CH1, 256, 0, stream>>>(ei, E, N, bcursor, rec);
    bucket_sort<<<(N + DPB - 1) / DPB, 256, 0, stream>>>(rec, bbase, offs, srcs, N, Etot);

    // Layer 1
    gemm_k128<128, float, __half><<<(N + 63) / 64, 256, 0, stream>>>(x, W1, h1, N);
    alphas1_kernel<<<(N + 3) / 4, 256, 0, stream>>>(h1, a_src1, a_dst1, as1, ad1, N);
    aggregate1<<<(N + 3) / 4, 256, 0, stream>>>(h1, as1, ad1, offs, srcs, b1, hmid, N);

    // Layer 2
    gemm_k128<64, __half, __half><<<(N + 63) / 64, 256, 0, stream>>>(hmid, W2, h2, N);
    alphas2_kernel<<<(N + 3) / 4, 256, 0, stream>>>(h2, a_src2, a_dst2, as2, ad2, N);
    aggregate2<<<(N + 3) / 4, 256, 0, stream>>>(h2, as2, ad2, offs, srcs, b2, out, N);
}

// Round 5
// 407.565 us; speedup vs baseline: 1.8915x; 1.0703x over previous
//
#include <hip/hip_runtime.h>
#include <hip/hip_fp16.h>
#include <math.h>

// GAT 2-layer, N=100000, E=1600000, F_IN=128, HID=128 (H=4,C=32), OUT=64 (H=1,C=64)
// R4 -> R5: (1) 32-bit gather addressing in aggregates (saddr form, kills
// v_mad_u64 chains). (2) predicated tail-free unroll-4 edge loop. (3) alphas
// fused into GEMM epilogue via shfl reduction (2 fewer dispatches, 38MB fewer
// reads). (4) hipMemsetAsync replaces zero kernel.

#define BSH 9      // log2 dsts per bucket
#define DPB 512    // dsts per bucket
#define NBK 256    // max buckets (covers N < 131072)
#define CH1 16384  // edges per block in bucket_scatter
#define LOG2E 1.44269504088896f

__device__ __forceinline__ float exp2_fast(float x) {
#if __has_builtin(__builtin_amdgcn_exp2f)
    return __builtin_amdgcn_exp2f(x);
#else
    return exp2f(x);
#endif
}

// ---------------- CSR build: bucketed counting sort ----------------

__global__ __launch_bounds__(256) void bucket_hist(const int* __restrict__ ei, int E, int N,
                                                   unsigned* __restrict__ bcount) {
    __shared__ unsigned hist[NBK];
    int t = threadIdx.x;
    hist[t] = 0;
    __syncthreads();
    int Etot = E + N;
    for (int k = blockIdx.x * 256 + t; k < Etot; k += gridDim.x * 256) {
        int d = (k < E) ? ei[E + k] : (k - E);
        atomicAdd(&hist[d >> BSH], 1u);
    }
    __syncthreads();
    unsigned c = hist[t];
    if (c) atomicAdd(&bcount[t], c);
}

__global__ void scan_buckets(const unsigned* __restrict__ bcount, unsigned* __restrict__ bbase,
                             unsigned* __restrict__ bcursor) {
    __shared__ unsigned s[NBK];
    int t = threadIdx.x;
    unsigned v = bcount[t];
    s[t] = v;
    __syncthreads();
    for (int o = 1; o < NBK; o <<= 1) {
        unsigned add = (t >= o) ? s[t - o] : 0;
        __syncthreads();
        s[t] += add;
        __syncthreads();
    }
    unsigned excl = s[t] - v;
    bbase[t] = excl;
    bcursor[t] = excl;
    if (t == NBK - 1) bbase[NBK] = excl + v;   // = Etot
}

__global__ __launch_bounds__(256) void bucket_scatter(const int* __restrict__ ei, int E, int N,
                                                      unsigned* __restrict__ bcursor,
                                                      uint2* __restrict__ rec) {
    __shared__ unsigned hist[NBK];
    __shared__ unsigned base[NBK];
    int t = threadIdx.x;
    hist[t] = 0;
    __syncthreads();
    int Etot = E + N;
    int k0 = blockIdx.x * CH1;
    int k1 = min(k0 + CH1, Etot);
    for (int k = k0 + t; k < k1; k += 256) {
        int d = (k < E) ? ei[E + k] : (k - E);
        atomicAdd(&hist[d >> BSH], 1u);
    }
    __syncthreads();
    unsigned c = hist[t];
    base[t] = c ? atomicAdd(&bcursor[t], c) : 0u;
    hist[t] = 0;
    __syncthreads();
    for (int k = k0 + t; k < k1; k += 256) {
        int s, d;
        if (k < E) { s = ei[k]; d = ei[E + k]; } else { s = d = k - E; }
        int b = d >> BSH;
        unsigned r = atomicAdd(&hist[b], 1u);
        rec[base[b] + r] = make_uint2((unsigned)s, (unsigned)d);
    }
}

__global__ __launch_bounds__(256) void bucket_sort(const uint2* __restrict__ rec,
                                                   const unsigned* __restrict__ bbase,
                                                   int* __restrict__ offs, int* __restrict__ srcs,
                                                   int N, int Etot) {
    __shared__ unsigned hist[DPB];
    __shared__ unsigned tsum[256];
    int t = threadIdx.x, bb = blockIdx.x;
    unsigned r0 = bbase[bb], r1 = bbase[bb + 1];
    hist[t] = 0;
    hist[t + 256] = 0;
    __syncthreads();
    int dlo = bb << BSH;
    for (unsigned k = r0 + t; k < r1; k += 256) {
        uint2 e = rec[k];
        atomicAdd(&hist[e.y - dlo], 1u);
    }
    __syncthreads();
    unsigned h0 = hist[2 * t], h1 = hist[2 * t + 1];
    tsum[t] = h0 + h1;
    __syncthreads();
    for (int o = 1; o < 256; o <<= 1) {
        unsigned a = (t >= o) ? tsum[t - o] : 0;
        __syncthreads();
        tsum[t] += a;
        __syncthreads();
    }
    unsigned tb = tsum[t] - (h0 + h1);
    int d0 = dlo + 2 * t;
    if (d0 < N) offs[d0] = (int)(r0 + tb);
    if (d0 + 1 < N) offs[d0 + 1] = (int)(r0 + tb + h0);
    hist[2 * t] = tb;            // reuse as relative cursors
    hist[2 * t + 1] = tb + h0;
    __syncthreads();
    for (unsigned k = r0 + t; k < r1; k += 256) {
        uint2 e = rec[k];
        unsigned r = atomicAdd(&hist[e.y - dlo], 1u);
        srcs[r0 + r] = (int)e.x;
    }
    if (bb == 0 && t == 0) offs[N] = Etot;
}

// ---------------- GEMM + fused alphas: C[M,NC] = A[M,128] * B[128,NC] ----------------
// Epilogue computes per-row, per-head dots with a_src/a_dst (pre-scaled by
// log2e) via shfl reduction over the tx lanes owning that head's columns.

template <int NC, int H, typename InT, typename OutT>
__global__ __launch_bounds__(256) void gemm_k128(const InT* __restrict__ A,
                                                 const float* __restrict__ B,
                                                 OutT* __restrict__ C,
                                                 const float* __restrict__ a_src,
                                                 const float* __restrict__ a_dst,
                                                 float* __restrict__ as,
                                                 float* __restrict__ ad, int M) {
    constexpr int BM = 64, BK = 32, K = 128;
    constexpr int TPR = NC / 4;          // threads covering NC cols via 4-col groups
    constexpr int R = BM / (256 / TPR);  // rows per thread (8 or 4)
    constexpr int TXH = TPR / H;         // tx lanes per head
    __shared__ float AsT[BK][BM + 4];    // +4 pad: breaks 16-way bank conflict on transpose store
    __shared__ float Bs[BK][NC];
    int tid = threadIdx.x;
    int tx = tid % TPR, ty = tid / TPR;
    int rowBase = blockIdx.x * BM;
    float acc[R][4] = {};
    for (int k0 = 0; k0 < K; k0 += BK) {
#pragma unroll
        for (int i = 0; i < 4; ++i) {
            int lin = tid + i * 256;     // 0..1023 2-elem slots
            int row = lin >> 4;          // 16 slots per row
            int kp = lin & 15;
            int grow = rowBase + row;
            if (grow >= M) grow = M - 1;
            float2 v;
            if constexpr (sizeof(InT) == 2) {
                __half2 hv = *reinterpret_cast<const __half2*>((const __half*)A + (size_t)grow * K + k0 + kp * 2);
                v = __half22float2(hv);
            } else {
                v = *reinterpret_cast<const float2*>((const float*)A + (size_t)grow * K + k0 + kp * 2);
            }
            AsT[kp * 2][row] = v.x;
            AsT[kp * 2 + 1][row] = v.y;
        }
#pragma unroll
        for (int i = 0; i < (BK * NC) / 1024; ++i) {
            int lin = tid + i * 256;     // float4 index
            int row = lin / (NC / 4);
            int col4 = lin % (NC / 4);
            float4 v = *reinterpret_cast<const float4*>(B + (size_t)(k0 + row) * NC + col4 * 4);
            *reinterpret_cast<float4*>(&Bs[row][col4 * 4]) = v;
        }
        __syncthreads();
#pragma unroll
        for (int kk = 0; kk < BK; ++kk) {
            float4 bv = *reinterpret_cast<const float4*>(&Bs[kk][tx * 4]);
            float a[R];
#pragma unroll
            for (int r4 = 0; r4 < R; r4 += 4) {
                float4 av = *reinterpret_cast<const float4*>(&AsT[kk][ty * R + r4]);
                a[r4] = av.x; a[r4 + 1] = av.y; a[r4 + 2] = av.z; a[r4 + 3] = av.w;
            }
#pragma unroll
            for (int r = 0; r < R; ++r) {
                acc[r][0] = fmaf(a[r], bv.x, acc[r][0]);
                acc[r][1] = fmaf(a[r], bv.y, acc[r][1]);
                acc[r][2] = fmaf(a[r], bv.z, acc[r][2]);
                acc[r][3] = fmaf(a[r], bv.w, acc[r][3]);
            }
        }
        __syncthreads();
    }
    // C store + fused alpha epilogue
    float4 asv = *reinterpret_cast<const float4*>(a_src + tx * 4);
    float4 adv = *reinterpret_cast<const float4*>(a_dst + tx * 4);
#pragma unroll
    for (int r = 0; r < R; ++r) {
        int grow = rowBase + ty * R + r;
        bool live = grow < M;
        if (live) {
            if constexpr (sizeof(OutT) == 2) {
                __half2 p0 = __floats2half2_rn(acc[r][0], acc[r][1]);
                __half2 p1 = __floats2half2_rn(acc[r][2], acc[r][3]);
                __half2* cp = reinterpret_cast<__half2*>((__half*)C + (size_t)grow * NC + tx * 4);
                cp[0] = p0;
                cp[1] = p1;
            } else {
                float4 v = make_float4(acc[r][0], acc[r][1], acc[r][2], acc[r][3]);
                *reinterpret_cast<float4*>((float*)C + (size_t)grow * NC + tx * 4) = v;
            }
        }
        float ps = acc[r][0] * asv.x + acc[r][1] * asv.y + acc[r][2] * asv.z + acc[r][3] * asv.w;
        float pd = acc[r][0] * adv.x + acc[r][1] * adv.y + acc[r][2] * adv.z + acc[r][3] * adv.w;
#pragma unroll
        for (int o = 1; o < TXH; o <<= 1) {
            ps += __shfl_xor(ps, o, 64);
            pd += __shfl_xor(pd, o, 64);
        }
        if ((tx & (TXH - 1)) == 0 && live) {
            int head = tx / TXH;
            as[(size_t)grow * H + head] = ps * LOG2E;
            ad[(size_t)grow * H + head] = pd * LOG2E;
        }
    }
}

// ---------------- aggregation (wave per dst node, predicated unroll-4) ----------------
// as/ad already in log2 domain; lrelu(t)=max(t,0.2t) commutes with positive scale.

__global__ __launch_bounds__(256) void aggregate1(const __half* __restrict__ h,
                                                  const float* __restrict__ as,
                                                  const float* __restrict__ ad,
                                                  const int* __restrict__ offs,
                                                  const int* __restrict__ srcs,
                                                  const float* __restrict__ bias,
                                                  __half* __restrict__ out, int N) {
    unsigned wid = (blockIdx.x * blockDim.x + threadIdx.x) >> 6;
    unsigned lane = threadIdx.x & 63;
    if (wid >= (unsigned)N) return;
    unsigned head = lane >> 4;
    float adv = ad[wid * 4u + head];
    int e0 = offs[wid], e1 = offs[wid + 1];
    int e1m1 = e1 - 1;                    // deg >= 1 (self-loop)
    const __half2* hp = reinterpret_cast<const __half2*>(h);
    float acc0 = 0.f, acc1 = 0.f, den = 0.f;
    for (int e = e0; e < e1; e += 4) {
        unsigned j0 = (unsigned)srcs[min(e, e1m1)];
        unsigned j1 = (unsigned)srcs[min(e + 1, e1m1)];
        unsigned j2 = (unsigned)srcs[min(e + 2, e1m1)];
        unsigned j3 = (unsigned)srcs[min(e + 3, e1m1)];
        float t0 = as[j0 * 4u + head] + adv;
        float t1 = as[j1 * 4u + head] + adv;
        float t2 = as[j2 * 4u + head] + adv;
        float t3 = as[j3 * 4u + head] + adv;
        __half2 h0 = hp[j0 * 64u + lane];
        __half2 h1 = hp[j1 * 64u + lane];
        __half2 h2 = hp[j2 * 64u + lane];
        __half2 h3 = hp[j3 * 64u + lane];
        float x0 = exp2_fast(fmaxf(t0, 0.2f * t0));
        float x1 = exp2_fast(fmaxf(t1, 0.2f * t1));
        float x2 = exp2_fast(fmaxf(t2, 0.2f * t2));
        float x3 = exp2_fast(fmaxf(t3, 0.2f * t3));
        x1 = (e + 1 < e1) ? x1 : 0.f;
        x2 = (e + 2 < e1) ? x2 : 0.f;
        x3 = (e + 3 < e1) ? x3 : 0.f;
        float2 f0 = __half22float2(h0), f1 = __half22float2(h1);
        float2 f2 = __half22float2(h2), f3 = __half22float2(h3);
        acc0 = fmaf(x0, f0.x, acc0); acc1 = fmaf(x0, f0.y, acc1);
        acc0 = fmaf(x1, f1.x, acc0); acc1 = fmaf(x1, f1.y, acc1);
        acc0 = fmaf(x2, f2.x, acc0); acc1 = fmaf(x2, f2.y, acc1);
        acc0 = fmaf(x3, f3.x, acc0); acc1 = fmaf(x3, f3.y, acc1);
        den += (x0 + x1) + (x2 + x3);
    }
    float r = 1.0f / (den + 1e-16f);
    float v0 = acc0 * r + bias[2 * lane];
    float v1 = acc1 * r + bias[2 * lane + 1];
    v0 = (v0 > 0.f) ? v0 : expm1f(v0);    // ELU
    v1 = (v1 > 0.f) ? v1 : expm1f(v1);
    reinterpret_cast<__half2*>(out)[wid * 64u + lane] = __floats2half2_rn(v0, v1);
}

__global__ __launch_bounds__(256) void aggregate2(const __half* __restrict__ h,
                                                  const float* __restrict__ as,
                                                  const float* __restrict__ ad,
                                                  const int* __restrict__ offs,
                                                  const int* __restrict__ srcs,
                                                  const float* __restrict__ bias,
                                                  float* __restrict__ out, int N) {
    unsigned wid = (blockIdx.x * blockDim.x + threadIdx.x) >> 6;
    unsigned lane = threadIdx.x & 63;
    if (wid >= (unsigned)N) return;
    float adv = ad[wid];
    int e0 = offs[wid], e1 = offs[wid + 1];
    int e1m1 = e1 - 1;
    float acc = 0.f, den = 0.f;
    for (int e = e0; e < e1; e += 4) {
        unsigned j0 = (unsigned)srcs[min(e, e1m1)];
        unsigned j1 = (unsigned)srcs[min(e + 1, e1m1)];
        unsigned j2 = (unsigned)srcs[min(e + 2, e1m1)];
        unsigned j3 = (unsigned)srcs[min(e + 3, e1m1)];
        float t0 = as[j0] + adv;
        float t1 = as[j1] + adv;
        float t2 = as[j2] + adv;
        float t3 = as[j3] + adv;
        __half h0 = h[j0 * 64u + lane];
        __half h1 = h[j1 * 64u + lane];
        __half h2 = h[j2 * 64u + lane];
        __half h3 = h[j3 * 64u + lane];
        float x0 = exp2_fast(fmaxf(t0, 0.2f * t0));
        float x1 = exp2_fast(fmaxf(t1, 0.2f * t1));
        float x2 = exp2_fast(fmaxf(t2, 0.2f * t2));
        float x3 = exp2_fast(fmaxf(t3, 0.2f * t3));
        x1 = (e + 1 < e1) ? x1 : 0.f;
        x2 = (e + 2 < e1) ? x2 : 0.f;
        x3 = (e + 3 < e1) ? x3 : 0.f;
        acc = fmaf(x0, __half2float(h0), acc);
        acc = fmaf(x1, __half2float(h1), acc);
        acc = fmaf(x2, __half2float(h2), acc);
        acc = fmaf(x3, __half2float(h3), acc);
        den += (x0 + x1) + (x2 + x3);
    }
    float r = 1.0f / (den + 1e-16f);
    out[wid * 64u + lane] = acc * r + bias[lane];
}

// ---------------- launch ----------------

extern "C" void kernel_launch(void* const* d_in, const int* in_sizes, int n_in,
                              void* d_out, int out_size, void* d_ws, size_t ws_size,
                              hipStream_t stream) {
    const float* x      = (const float*)d_in[0];
    const int*   ei     = (const int*)d_in[1];
    const float* W1     = (const float*)d_in[2];
    const float* a_src1 = (const float*)d_in[3];
    const float* a_dst1 = (const float*)d_in[4];
    const float* b1     = (const float*)d_in[5];
    const float* W2     = (const float*)d_in[6];
    const float* a_src2 = (const float*)d_in[7];
    const float* a_dst2 = (const float*)d_in[8];
    const float* b2     = (const float*)d_in[9];
    float* out = (float*)d_out;

    const int N = out_size / 64;          // 100000
    const int E = in_sizes[1] / 2;        // 1600000
    const int Etot = E + N;

    size_t off = 0;
    auto carve = [&](size_t bytes) -> void* {
        void* p = (char*)d_ws + off;
        off += (bytes + 255) & ~(size_t)255;
        return p;
    };
    __half* h1      = (__half*)carve((size_t)N * 128 * 2);   // fp16 h, layer 1
    __half* hmid    = (__half*)carve((size_t)N * 128 * 2);   // fp16 ELU output
    float* as1      = (float*)carve((size_t)N * 4 * 4);
    float* ad1      = (float*)carve((size_t)N * 4 * 4);
    float* as2      = (float*)carve((size_t)N * 4);
    float* ad2      = (float*)carve((size_t)N * 4);
    int*   offs     = (int*)carve((size_t)(N + 1) * 4);
    int*   srcs     = (int*)carve((size_t)Etot * 4);
    uint2* rec      = (uint2*)carve((size_t)Etot * 8);
    unsigned* bcount  = (unsigned*)carve(NBK * 4);
    unsigned* bbase   = (unsigned*)carve((NBK + 1) * 4);
    unsigned* bcursor = (unsigned*)carve(NBK * 4);
    __half* h2      = h1;    // alias: h1 dead after aggregate1

    // CSR build via bucketed counting sort (shared by both layers)
    hipMemsetAsync(bcount, 0, NBK * sizeof(unsigned), stream);
    bucket_hist<<<128, 256, 0, stream>>>(ei, E, N, bcount);
    scan_buckets<<<1, 256, 0, stream>>>(bcount, bbase, bcursor);
    bucket_scatter<<<(Etot + CH1 - 1) / CH1, 256, 0, stream>>>(ei, E, N, bcursor, rec);
    bucket_sort<<<(N + DPB - 1) / DPB, 256, 0, stream>>>(rec, bbase, offs, srcs, N, Etot);

    // Layer 1 (alphas fused into gemm epilogue)
    gemm_k128<128, 4, float, __half><<<(N + 63) / 64, 256, 0, stream>>>(
        x, W1, h1, a_src1, a_dst1, as1, ad1, N);
    aggregate1<<<(N + 3) / 4, 256, 0, stream>>>(h1, as1, ad1, offs, srcs, b1, hmid, N);

    // Layer 2
    gemm_k128<64, 1, __half, __half><<<(N + 63) / 64, 256, 0, stream>>>(
        hmid, W2, h2, a_src2, a_dst2, as2, ad2, N);
    aggregate2<<<(N + 3) / 4, 256, 0, stream>>>(h2, as2, ad2, offs, srcs, b2, out, N);
}

// Round 6
// 390.046 us; speedup vs baseline: 1.9765x; 1.0449x over previous
//
#include <hip/hip_runtime.h>
#include <hip/hip_fp16.h>
#include <math.h>
#include <string.h>

// GAT 2-layer, N=100000, E=1600000, F_IN=128, HID=128 (H=4,C=32), OUT=64 (H=1,C=64)
// R5 -> R6: aggregation restructured to 4 dst-nodes per wave (16 lanes/node):
// one loop iteration = 4 edges with ONE set of per-edge instructions (srcs/as/h
// loads, exp, t-compute amortized 4x). Loop to max-deg of the 4 groups,
// predicated; unroll-2 for load ILP. agg1: 8 ch/lane (16B gather); agg2:
// 4 ch/lane (8B gather). Everything else unchanged from R5.

#define BSH 9      // log2 dsts per bucket
#define DPB 512    // dsts per bucket
#define NBK 256    // max buckets (covers N < 131072)
#define CH1 16384  // edges per block in bucket_scatter
#define LOG2E 1.44269504088896f

__device__ __forceinline__ float exp2_fast(float x) {
#if __has_builtin(__builtin_amdgcn_exp2f)
    return __builtin_amdgcn_exp2f(x);
#else
    return exp2f(x);
#endif
}

// ---------------- CSR build: bucketed counting sort ----------------

__global__ __launch_bounds__(256) void bucket_hist(const int* __restrict__ ei, int E, int N,
                                                   unsigned* __restrict__ bcount) {
    __shared__ unsigned hist[NBK];
    int t = threadIdx.x;
    hist[t] = 0;
    __syncthreads();
    int Etot = E + N;
    for (int k = blockIdx.x * 256 + t; k < Etot; k += gridDim.x * 256) {
        int d = (k < E) ? ei[E + k] : (k - E);
        atomicAdd(&hist[d >> BSH], 1u);
    }
    __syncthreads();
    unsigned c = hist[t];
    if (c) atomicAdd(&bcount[t], c);
}

__global__ void scan_buckets(const unsigned* __restrict__ bcount, unsigned* __restrict__ bbase,
                             unsigned* __restrict__ bcursor) {
    __shared__ unsigned s[NBK];
    int t = threadIdx.x;
    unsigned v = bcount[t];
    s[t] = v;
    __syncthreads();
    for (int o = 1; o < NBK; o <<= 1) {
        unsigned add = (t >= o) ? s[t - o] : 0;
        __syncthreads();
        s[t] += add;
        __syncthreads();
    }
    unsigned excl = s[t] - v;
    bbase[t] = excl;
    bcursor[t] = excl;
    if (t == NBK - 1) bbase[NBK] = excl + v;   // = Etot
}

__global__ __launch_bounds__(256) void bucket_scatter(const int* __restrict__ ei, int E, int N,
                                                      unsigned* __restrict__ bcursor,
                                                      uint2* __restrict__ rec) {
    __shared__ unsigned hist[NBK];
    __shared__ unsigned base[NBK];
    int t = threadIdx.x;
    hist[t] = 0;
    __syncthreads();
    int Etot = E + N;
    int k0 = blockIdx.x * CH1;
    int k1 = min(k0 + CH1, Etot);
    for (int k = k0 + t; k < k1; k += 256) {
        int d = (k < E) ? ei[E + k] : (k - E);
        atomicAdd(&hist[d >> BSH], 1u);
    }
    __syncthreads();
    unsigned c = hist[t];
    base[t] = c ? atomicAdd(&bcursor[t], c) : 0u;
    hist[t] = 0;
    __syncthreads();
    for (int k = k0 + t; k < k1; k += 256) {
        int s, d;
        if (k < E) { s = ei[k]; d = ei[E + k]; } else { s = d = k - E; }
        int b = d >> BSH;
        unsigned r = atomicAdd(&hist[b], 1u);
        rec[base[b] + r] = make_uint2((unsigned)s, (unsigned)d);
    }
}

__global__ __launch_bounds__(256) void bucket_sort(const uint2* __restrict__ rec,
                                                   const unsigned* __restrict__ bbase,
                                                   int* __restrict__ offs, int* __restrict__ srcs,
                                                   int N, int Etot) {
    __shared__ unsigned hist[DPB];
    __shared__ unsigned tsum[256];
    int t = threadIdx.x, bb = blockIdx.x;
    unsigned r0 = bbase[bb], r1 = bbase[bb + 1];
    hist[t] = 0;
    hist[t + 256] = 0;
    __syncthreads();
    int dlo = bb << BSH;
    for (unsigned k = r0 + t; k < r1; k += 256) {
        uint2 e = rec[k];
        atomicAdd(&hist[e.y - dlo], 1u);
    }
    __syncthreads();
    unsigned h0 = hist[2 * t], h1 = hist[2 * t + 1];
    tsum[t] = h0 + h1;
    __syncthreads();
    for (int o = 1; o < 256; o <<= 1) {
        unsigned a = (t >= o) ? tsum[t - o] : 0;
        __syncthreads();
        tsum[t] += a;
        __syncthreads();
    }
    unsigned tb = tsum[t] - (h0 + h1);
    int d0 = dlo + 2 * t;
    if (d0 < N) offs[d0] = (int)(r0 + tb);
    if (d0 + 1 < N) offs[d0 + 1] = (int)(r0 + tb + h0);
    hist[2 * t] = tb;            // reuse as relative cursors
    hist[2 * t + 1] = tb + h0;
    __syncthreads();
    for (unsigned k = r0 + t; k < r1; k += 256) {
        uint2 e = rec[k];
        unsigned r = atomicAdd(&hist[e.y - dlo], 1u);
        srcs[r0 + r] = (int)e.x;
    }
    if (bb == 0 && t == 0) offs[N] = Etot;
}

// ---------------- GEMM + fused alphas: C[M,NC] = A[M,128] * B[128,NC] ----------------

template <int NC, int H, typename InT, typename OutT>
__global__ __launch_bounds__(256) void gemm_k128(const InT* __restrict__ A,
                                                 const float* __restrict__ B,
                                                 OutT* __restrict__ C,
                                                 const float* __restrict__ a_src,
                                                 const float* __restrict__ a_dst,
                                                 float* __restrict__ as,
                                                 float* __restrict__ ad, int M) {
    constexpr int BM = 64, BK = 32, K = 128;
    constexpr int TPR = NC / 4;          // threads covering NC cols via 4-col groups
    constexpr int R = BM / (256 / TPR);  // rows per thread (8 or 4)
    constexpr int TXH = TPR / H;         // tx lanes per head
    __shared__ float AsT[BK][BM + 4];    // +4 pad: breaks 16-way bank conflict on transpose store
    __shared__ float Bs[BK][NC];
    int tid = threadIdx.x;
    int tx = tid % TPR, ty = tid / TPR;
    int rowBase = blockIdx.x * BM;
    float acc[R][4] = {};
    for (int k0 = 0; k0 < K; k0 += BK) {
#pragma unroll
        for (int i = 0; i < 4; ++i) {
            int lin = tid + i * 256;     // 0..1023 2-elem slots
            int row = lin >> 4;          // 16 slots per row
            int kp = lin & 15;
            int grow = rowBase + row;
            if (grow >= M) grow = M - 1;
            float2 v;
            if constexpr (sizeof(InT) == 2) {
                __half2 hv = *reinterpret_cast<const __half2*>((const __half*)A + (size_t)grow * K + k0 + kp * 2);
                v = __half22float2(hv);
            } else {
                v = *reinterpret_cast<const float2*>((const float*)A + (size_t)grow * K + k0 + kp * 2);
            }
            AsT[kp * 2][row] = v.x;
            AsT[kp * 2 + 1][row] = v.y;
        }
#pragma unroll
        for (int i = 0; i < (BK * NC) / 1024; ++i) {
            int lin = tid + i * 256;     // float4 index
            int row = lin / (NC / 4);
            int col4 = lin % (NC / 4);
            float4 v = *reinterpret_cast<const float4*>(B + (size_t)(k0 + row) * NC + col4 * 4);
            *reinterpret_cast<float4*>(&Bs[row][col4 * 4]) = v;
        }
        __syncthreads();
#pragma unroll
        for (int kk = 0; kk < BK; ++kk) {
            float4 bv = *reinterpret_cast<const float4*>(&Bs[kk][tx * 4]);
            float a[R];
#pragma unroll
            for (int r4 = 0; r4 < R; r4 += 4) {
                float4 av = *reinterpret_cast<const float4*>(&AsT[kk][ty * R + r4]);
                a[r4] = av.x; a[r4 + 1] = av.y; a[r4 + 2] = av.z; a[r4 + 3] = av.w;
            }
#pragma unroll
            for (int r = 0; r < R; ++r) {
                acc[r][0] = fmaf(a[r], bv.x, acc[r][0]);
                acc[r][1] = fmaf(a[r], bv.y, acc[r][1]);
                acc[r][2] = fmaf(a[r], bv.z, acc[r][2]);
                acc[r][3] = fmaf(a[r], bv.w, acc[r][3]);
            }
        }
        __syncthreads();
    }
    // C store + fused alpha epilogue
    float4 asv = *reinterpret_cast<const float4*>(a_src + tx * 4);
    float4 adv = *reinterpret_cast<const float4*>(a_dst + tx * 4);
#pragma unroll
    for (int r = 0; r < R; ++r) {
        int grow = rowBase + ty * R + r;
        bool live = grow < M;
        if (live) {
            if constexpr (sizeof(OutT) == 2) {
                __half2 p0 = __floats2half2_rn(acc[r][0], acc[r][1]);
                __half2 p1 = __floats2half2_rn(acc[r][2], acc[r][3]);
                __half2* cp = reinterpret_cast<__half2*>((__half*)C + (size_t)grow * NC + tx * 4);
                cp[0] = p0;
                cp[1] = p1;
            } else {
                float4 v = make_float4(acc[r][0], acc[r][1], acc[r][2], acc[r][3]);
                *reinterpret_cast<float4*>((float*)C + (size_t)grow * NC + tx * 4) = v;
            }
        }
        float ps = acc[r][0] * asv.x + acc[r][1] * asv.y + acc[r][2] * asv.z + acc[r][3] * asv.w;
        float pd = acc[r][0] * adv.x + acc[r][1] * adv.y + acc[r][2] * adv.z + acc[r][3] * adv.w;
#pragma unroll
        for (int o = 1; o < TXH; o <<= 1) {
            ps += __shfl_xor(ps, o, 64);
            pd += __shfl_xor(pd, o, 64);
        }
        if ((tx & (TXH - 1)) == 0 && live) {
            int head = tx / TXH;
            as[(size_t)grow * H + head] = ps * LOG2E;
            ad[(size_t)grow * H + head] = pd * LOG2E;
        }
    }
}

// ---------------- aggregation: 4 dst nodes per wave, 16 lanes per node ----------------
// as/ad in log2 domain; lrelu(t)=max(t,0.2t) commutes with positive scale.
// Per loop iteration: 4 edges (one per 16-lane group) with one set of wave
// instructions. Unroll-2 for load ILP. Loop bound = max deg of the 4 groups.

template <int H, int F, bool DOELU, typename OutT>
__global__ __launch_bounds__(256) void aggregateQ(const __half* __restrict__ h,
                                                  const float* __restrict__ as,
                                                  const float* __restrict__ ad,
                                                  const int* __restrict__ offs,
                                                  const int* __restrict__ srcs,
                                                  const float* __restrict__ bias,
                                                  OutT* __restrict__ out, int N) {
    constexpr int CPL = F / 16;     // channels per lane (8 or 4)
    constexpr int NH2 = CPL / 2;    // half2 per lane (4 or 2)
    unsigned wave = (blockIdx.x * blockDim.x + threadIdx.x) >> 6;
    unsigned lane = threadIdx.x & 63;
    unsigned lig = lane & 15;       // lane in group
    unsigned node = wave * 4u + (lane >> 4);
    bool live = node < (unsigned)N;
    unsigned nc = live ? node : (unsigned)(N - 1);
    unsigned head = (lig * CPL) / (F / H);   // H=4: lig>>2; H=1: 0
    float adv = ad[nc * H + head];
    int e0 = offs[nc], e1 = offs[nc + 1];
    int deg = e1 - e0, e1m1 = e1 - 1;
    int md = deg;
    md = max(md, __shfl_xor(md, 16, 64));
    md = max(md, __shfl_xor(md, 32, 64));
    float2 acc[NH2] = {};
    float den = 0.f;
    for (int k = 0; k < md; k += 2) {
        unsigned ja = (unsigned)srcs[min(e0 + k, e1m1)];
        unsigned jb = (unsigned)srcs[min(e0 + k + 1, e1m1)];
        float ta = as[ja * H + head] + adv;
        float tb = as[jb * H + head] + adv;
        __half2 ha[NH2], hb[NH2];
        if constexpr (NH2 == 4) {
            uint4 va = *reinterpret_cast<const uint4*>(h + ja * (unsigned)F + lig * CPL);
            uint4 vb = *reinterpret_cast<const uint4*>(h + jb * (unsigned)F + lig * CPL);
            memcpy(ha, &va, 16);
            memcpy(hb, &vb, 16);
        } else {
            uint2 va = *reinterpret_cast<const uint2*>(h + ja * (unsigned)F + lig * CPL);
            uint2 vb = *reinterpret_cast<const uint2*>(h + jb * (unsigned)F + lig * CPL);
            memcpy(ha, &va, 8);
            memcpy(hb, &vb, 8);
        }
        float xa = exp2_fast(fmaxf(ta, 0.2f * ta));
        float xb = exp2_fast(fmaxf(tb, 0.2f * tb));
        xa = (k < deg) ? xa : 0.f;
        xb = (k + 1 < deg) ? xb : 0.f;
#pragma unroll
        for (int q = 0; q < NH2; ++q) {
            float2 fa = __half22float2(ha[q]);
            float2 fb = __half22float2(hb[q]);
            acc[q].x = fmaf(xa, fa.x, acc[q].x);
            acc[q].y = fmaf(xa, fa.y, acc[q].y);
            acc[q].x = fmaf(xb, fb.x, acc[q].x);
            acc[q].y = fmaf(xb, fb.y, acc[q].y);
        }
        den += xa + xb;
    }
    float r = 1.0f / (den + 1e-16f);
    if (!live) return;
    const float* bp = bias + lig * CPL;
    if constexpr (sizeof(OutT) == 2) {
        __half2 st[NH2];
#pragma unroll
        for (int q = 0; q < NH2; ++q) {
            float v0 = acc[q].x * r + bp[2 * q];
            float v1 = acc[q].y * r + bp[2 * q + 1];
            if constexpr (DOELU) {
                v0 = (v0 > 0.f) ? v0 : expm1f(v0);
                v1 = (v1 > 0.f) ? v1 : expm1f(v1);
            }
            st[q] = __floats2half2_rn(v0, v1);
        }
        if constexpr (NH2 == 4) {
            uint4 v; memcpy(&v, st, 16);
            *reinterpret_cast<uint4*>((__half*)out + node * (unsigned)F + lig * CPL) = v;
        } else {
            uint2 v; memcpy(&v, st, 8);
            *reinterpret_cast<uint2*>((__half*)out + node * (unsigned)F + lig * CPL) = v;
        }
    } else {
        float vs[CPL];
#pragma unroll
        for (int q = 0; q < NH2; ++q) {
            float v0 = acc[q].x * r + bp[2 * q];
            float v1 = acc[q].y * r + bp[2 * q + 1];
            if constexpr (DOELU) {
                v0 = (v0 > 0.f) ? v0 : expm1f(v0);
                v1 = (v1 > 0.f) ? v1 : expm1f(v1);
            }
            vs[2 * q] = v0;
            vs[2 * q + 1] = v1;
        }
#pragma unroll
        for (int q4 = 0; q4 < CPL; q4 += 4) {
            float4 v = make_float4(vs[q4], vs[q4 + 1], vs[q4 + 2], vs[q4 + 3]);
            *reinterpret_cast<float4*>((float*)out + node * (unsigned)F + lig * CPL + q4) = v;
        }
    }
}

// ---------------- launch ----------------

extern "C" void kernel_launch(void* const* d_in, const int* in_sizes, int n_in,
                              void* d_out, int out_size, void* d_ws, size_t ws_size,
                              hipStream_t stream) {
    const float* x      = (const float*)d_in[0];
    const int*   ei     = (const int*)d_in[1];
    const float* W1     = (const float*)d_in[2];
    const float* a_src1 = (const float*)d_in[3];
    const float* a_dst1 = (const float*)d_in[4];
    const float* b1     = (const float*)d_in[5];
    const float* W2     = (const float*)d_in[6];
    const float* a_src2 = (const float*)d_in[7];
    const float* a_dst2 = (const float*)d_in[8];
    const float* b2     = (const float*)d_in[9];
    float* out = (float*)d_out;

    const int N = out_size / 64;          // 100000
    const int E = in_sizes[1] / 2;        // 1600000
    const int Etot = E + N;

    size_t off = 0;
    auto carve = [&](size_t bytes) -> void* {
        void* p = (char*)d_ws + off;
        off += (bytes + 255) & ~(size_t)255;
        return p;
    };
    __half* h1      = (__half*)carve((size_t)N * 128 * 2);   // fp16 h, layer 1
    __half* hmid    = (__half*)carve((size_t)N * 128 * 2);   // fp16 ELU output
    float* as1      = (float*)carve((size_t)N * 4 * 4);
    float* ad1      = (float*)carve((size_t)N * 4 * 4);
    float* as2      = (float*)carve((size_t)N * 4);
    float* ad2      = (float*)carve((size_t)N * 4);
    int*   offs     = (int*)carve((size_t)(N + 1) * 4);
    int*   srcs     = (int*)carve((size_t)Etot * 4);
    uint2* rec      = (uint2*)carve((size_t)Etot * 8);
    unsigned* bcount  = (unsigned*)carve(NBK * 4);
    unsigned* bbase   = (unsigned*)carve((NBK + 1) * 4);
    unsigned* bcursor = (unsigned*)carve(NBK * 4);
    __half* h2      = h1;    // alias: h1 dead after aggregate1

    // CSR build via bucketed counting sort (shared by both layers)
    hipMemsetAsync(bcount, 0, NBK * sizeof(unsigned), stream);
    bucket_hist<<<128, 256, 0, stream>>>(ei, E, N, bcount);
    scan_buckets<<<1, 256, 0, stream>>>(bcount, bbase, bcursor);
    bucket_scatter<<<(Etot + CH1 - 1) / CH1, 256, 0, stream>>>(ei, E, N, bcursor, rec);
    bucket_sort<<<(N + DPB - 1) / DPB, 256, 0, stream>>>(rec, bbase, offs, srcs, N, Etot);

    // Layer 1 (alphas fused into gemm epilogue)
    gemm_k128<128, 4, float, __half><<<(N + 63) / 64, 256, 0, stream>>>(
        x, W1, h1, a_src1, a_dst1, as1, ad1, N);
    aggregateQ<4, 128, true, __half><<<(N + 15) / 16, 256, 0, stream>>>(
        h1, as1, ad1, offs, srcs, b1, hmid, N);

    // Layer 2
    gemm_k128<64, 1, __half, __half><<<(N + 63) / 64, 256, 0, stream>>>(
        hmid, W2, h2, a_src2, a_dst2, as2, ad2, N);
    aggregateQ<1, 64, false, float><<<(N + 15) / 16, 256, 0, stream>>>(
        h2, as2, ad2, offs, srcs, b2, out, N);
}